// Round 2
// baseline (12510.077 us; speedup 1.0000x reference)
//
#include <hip/hip_runtime.h>

#define DEV __device__ __forceinline__

constexpr int NN = 50000;
constexpr int NE = 800000;
constexpr int NG = 1024;
constexpr int EMB = 256;
constexpr int NH = 4;
constexpr int HE = 1024;   // NH*EMB
constexpr int NL = 4;
constexpr int TASKS = 128;
constexpr int SLICES = 16;
constexpr int CHUNK = (NN + SLICES - 1) / SLICES; // 3125
constexpr int GB32 = (NN + 31) / 32;              // 1563

using u16 = unsigned short;
using u32 = unsigned int;

DEV u16 f2bf(float f) {
  u32 u = __float_as_uint(f);
  u32 r = (u + 0x7FFFu + ((u >> 16) & 1u)) >> 16;
  return (u16)r;
}
DEV float bf2f(u16 s) { return __uint_as_float(((u32)s) << 16); }

// ---------------- utility ----------------

__global__ void k_zero(u32* __restrict__ p, int n) {
  int i = blockIdx.x * 256 + threadIdx.x;
  if (i < n) p[i] = 0u;
}

__global__ void k_fill(float* __restrict__ p, int n, float v) {
  int i = blockIdx.x * 256 + threadIdx.x;
  if (i < n) p[i] = v;
}

// ---------------- setup kernels ----------------

__global__ void k_atom(const int* __restrict__ x, const float* __restrict__ aemb,
                       float* __restrict__ h) {
  int n = blockIdx.x, d = threadIdx.x;
  const int* xr = x + n * 9;
  float acc = 0.f;
#pragma unroll
  for (int f = 0; f < 9; ++f) acc += aemb[(f * 100 + xr[f]) * EMB + d];
  h[(size_t)n * EMB + d] = acc;
}

__global__ void k_deg(const int* __restrict__ row, const int* __restrict__ col,
                      int* __restrict__ deg_i, int* __restrict__ deg_j) {
  int e = blockIdx.x * 256 + threadIdx.x;
  if (e < NE) {
    atomicAdd(&deg_i[row[e]], 1);
    atomicAdd(&deg_j[col[e]], 1);
  }
}

__global__ void k_dinv(const int* __restrict__ deg_i, const int* __restrict__ deg_j,
                       float* __restrict__ di, float* __restrict__ dj) {
  int n = blockIdx.x * 256 + threadIdx.x;
  if (n < NN) {
    di[n] = deg_i[n] > 0 ? rsqrtf((float)deg_i[n]) : 0.f;
    dj[n] = deg_j[n] > 0 ? rsqrtf((float)deg_j[n]) : 0.f;
  }
}

__global__ void k_scan(const int* __restrict__ deg, int* __restrict__ offs) {
  __shared__ int tot[1024];
  int t = threadIdx.x;
  constexpr int PER = (NN + 1023) / 1024; // 49
  int lo = t * PER, hi = lo + PER;
  if (hi > NN) hi = NN;
  int s = 0;
  for (int i = lo; i < hi; ++i) s += deg[i];
  tot[t] = s;
  __syncthreads();
  for (int off = 1; off < 1024; off <<= 1) {
    int v = (t >= off) ? tot[t - off] : 0;
    __syncthreads();
    tot[t] += v;
    __syncthreads();
  }
  int run = (t == 0) ? 0 : tot[t - 1];
  for (int i = lo; i < hi; ++i) { offs[i] = run; run += deg[i]; }
  if (t == 0) offs[NN] = NE;
}

__global__ void k_csr(const int* __restrict__ row, const int* __restrict__ col,
                      const int* __restrict__ eattr, const float* __restrict__ di,
                      const float* __restrict__ dj, const int* __restrict__ offs,
                      int* __restrict__ cursor, int* __restrict__ csr_col,
                      float* __restrict__ csr_adj, int* __restrict__ csr_pack) {
  int e = blockIdx.x * 256 + threadIdx.x;
  if (e >= NE) return;
  int r = row[e], c = col[e];
  int slot = offs[r] + atomicAdd(&cursor[r], 1);
  csr_col[slot] = c;
  csr_adj[slot] = di[r] * dj[c];
  csr_pack[slot] = eattr[e * 3] | (eattr[e * 3 + 1] << 8) | (eattr[e * 3 + 2] << 16);
}

__global__ void k_gcnt(const int* __restrict__ batch, float* __restrict__ gcnt) {
  int n = blockIdx.x * 256 + threadIdx.x;
  if (n < NN) atomicAdd(&gcnt[batch[n]], 1.f);
}

// ---------------- per-layer kernels ----------------

__global__ void k_message(const float* __restrict__ bond, const int* __restrict__ offs,
                          const float* __restrict__ csr_adj, const int* __restrict__ csr_pack,
                          u16* __restrict__ msg) {
  __shared__ float tab[3 * 10 * EMB]; // 30 KB
  int tid = threadIdx.x;
  for (int i = tid; i < 3 * 10 * EMB; i += 256) tab[i] = bond[i];
  __syncthreads();
  int n0 = blockIdx.x * 16;
  for (int nn = 0; nn < 16; ++nn) {
    int n = n0 + nn;
    int e0 = offs[n], e1 = offs[n + 1];
    float acc = 0.f;
    for (int s = e0; s < e1; ++s) {
      float a = csr_adj[s];
      int pk = csr_pack[s];
      int a0 = pk & 255, a1 = (pk >> 8) & 255, a2 = (pk >> 16) & 255;
      acc += a * (tab[a0 * EMB + tid] + tab[(10 + a1) * EMB + tid] + tab[(20 + a2) * EMB + tid]);
    }
    msg[(size_t)n * EMB + tid] = f2bf(acc);
  }
}

// k projection + per-head L2 normalize + bf16 store + ks_sum + h_sum
__global__ __launch_bounds__(256) void k_projk(
    const float* __restrict__ h, const float* __restrict__ wk, const float* __restrict__ bk,
    u16* __restrict__ kn, float* __restrict__ ks_sum, float* __restrict__ h_sum) {
  __shared__ float hT[EMB * 33];
  __shared__ float red[4][EMB];
  int tid = threadIdx.x;
  int og = tid & 63, wv = tid >> 6;
  int n0 = blockIdx.x * 32;
  for (int it = 0; it < 32; ++it) {
    int r = n0 + it;
    hT[tid * 33 + it] = (r < NN) ? h[(size_t)r * EMB + tid] : 0.f;
  }
  __syncthreads();
  { // column sums of h (for h.sum(0))
    float s = 0.f;
    for (int r = 0; r < 32; ++r) s += hT[tid * 33 + r];
    atomicAdd(&h_sum[tid], s);
  }
  for (int hd = 0; hd < NH; ++hd) {
    float acc[8][4] = {};
    const float* wp = wk + hd * 256 + og * 4;
#pragma unroll 4
    for (int k = 0; k < EMB; ++k) {
      float4 bv = *reinterpret_cast<const float4*>(wp + (size_t)k * HE);
      const float* ap = &hT[k * 33 + wv * 8];
#pragma unroll
      for (int r = 0; r < 8; ++r) {
        float a = ap[r];
        acc[r][0] += a * bv.x; acc[r][1] += a * bv.y;
        acc[r][2] += a * bv.z; acc[r][3] += a * bv.w;
      }
    }
    float4 bias = *reinterpret_cast<const float4*>(bk + hd * 256 + og * 4);
    float colsum[4] = {0.f, 0.f, 0.f, 0.f};
#pragma unroll
    for (int r = 0; r < 8; ++r) {
      float v0 = acc[r][0] + bias.x, v1 = acc[r][1] + bias.y;
      float v2 = acc[r][2] + bias.z, v3 = acc[r][3] + bias.w;
      float nr = v0 * v0 + v1 * v1 + v2 * v2 + v3 * v3;
#pragma unroll
      for (int m = 1; m < 64; m <<= 1) nr += __shfl_xor(nr, m, 64);
      float rn = rsqrtf(nr);
      v0 *= rn; v1 *= rn; v2 *= rn; v3 *= rn;
      int rowi = n0 + wv * 8 + r;
      if (rowi < NN) {
        ushort4 pk;
        pk.x = f2bf(v0); pk.y = f2bf(v1); pk.z = f2bf(v2); pk.w = f2bf(v3);
        *reinterpret_cast<ushort4*>(kn + (size_t)rowi * HE + hd * 256 + og * 4) = pk;
        colsum[0] += v0; colsum[1] += v1; colsum[2] += v2; colsum[3] += v3;
      }
    }
    __syncthreads();
#pragma unroll
    for (int j = 0; j < 4; ++j) red[wv][og * 4 + j] = colsum[j];
    __syncthreads();
    if (wv == 0) {
#pragma unroll
      for (int j = 0; j < 4; ++j) {
        int c = og * 4 + j;
        atomicAdd(&ks_sum[hd * 256 + c], red[0][c] + red[1][c] + red[2][c] + red[3][c]);
      }
    }
  }
}

// kvs partials: part[sl][j][d] = sum_{n in slice} kn[n][j] * h[n][d]
__global__ __launch_bounds__(256) void k_kvs(const u16* __restrict__ kn,
                                             const float* __restrict__ h,
                                             float* __restrict__ part) {
  __shared__ float As[32 * 64];
  __shared__ float Bs[32 * 64];
  int tid = threadIdx.x;
  int tx = tid & 15, ty = tid >> 4;
  int d0 = blockIdx.x * 64, j0 = blockIdx.y * 64, sl = blockIdx.z;
  int nb = sl * CHUNK, neend = nb + CHUNK;
  if (neend > NN) neend = NN;
  float acc[4][4] = {};
  int kk = tid >> 3;
  int off8 = (tid & 7) * 8;
  for (int k0 = nb; k0 < neend; k0 += 32) {
    int row = k0 + kk;
    if (row < neend) {
      uint4 raw = *reinterpret_cast<const uint4*>(kn + (size_t)row * HE + j0 + off8);
      As[kk * 64 + off8 + 0] = bf2f(raw.x & 0xffff);
      As[kk * 64 + off8 + 1] = bf2f(raw.x >> 16);
      As[kk * 64 + off8 + 2] = bf2f(raw.y & 0xffff);
      As[kk * 64 + off8 + 3] = bf2f(raw.y >> 16);
      As[kk * 64 + off8 + 4] = bf2f(raw.z & 0xffff);
      As[kk * 64 + off8 + 5] = bf2f(raw.z >> 16);
      As[kk * 64 + off8 + 6] = bf2f(raw.w & 0xffff);
      As[kk * 64 + off8 + 7] = bf2f(raw.w >> 16);
      float4 b0 = *reinterpret_cast<const float4*>(h + (size_t)row * EMB + d0 + off8);
      float4 b1 = *reinterpret_cast<const float4*>(h + (size_t)row * EMB + d0 + off8 + 4);
      *reinterpret_cast<float4*>(&Bs[kk * 64 + off8]) = b0;
      *reinterpret_cast<float4*>(&Bs[kk * 64 + off8 + 4]) = b1;
    } else {
#pragma unroll
      for (int q = 0; q < 8; ++q) { As[kk * 64 + off8 + q] = 0.f; Bs[kk * 64 + off8 + q] = 0.f; }
    }
    __syncthreads();
#pragma unroll
    for (int k2 = 0; k2 < 32; ++k2) {
      float4 a = *reinterpret_cast<const float4*>(&As[k2 * 64 + ty * 4]);
      float4 b = *reinterpret_cast<const float4*>(&Bs[k2 * 64 + tx * 4]);
      acc[0][0] += a.x * b.x; acc[0][1] += a.x * b.y; acc[0][2] += a.x * b.z; acc[0][3] += a.x * b.w;
      acc[1][0] += a.y * b.x; acc[1][1] += a.y * b.y; acc[1][2] += a.y * b.z; acc[1][3] += a.y * b.w;
      acc[2][0] += a.z * b.x; acc[2][1] += a.z * b.y; acc[2][2] += a.z * b.z; acc[2][3] += a.z * b.w;
      acc[3][0] += a.w * b.x; acc[3][1] += a.w * b.y; acc[3][2] += a.w * b.z; acc[3][3] += a.w * b.w;
    }
    __syncthreads();
  }
  float* op = part + (size_t)sl * HE * EMB;
#pragma unroll
  for (int i = 0; i < 4; ++i) {
    float4 o4 = {acc[i][0], acc[i][1], acc[i][2], acc[i][3]};
    *reinterpret_cast<float4*>(op + (size_t)(j0 + ty * 4 + i) * EMB + d0 + tx * 4) = o4;
  }
}

__global__ void k_kvs_red(const float* __restrict__ part, float* __restrict__ kvs) {
  int i = blockIdx.x * 256 + threadIdx.x;
  float s = 0.f;
#pragma unroll
  for (int sl = 0; sl < SLICES; ++sl) s += part[(size_t)sl * HE * EMB + i];
  kvs[i] = s;
}

// M[hd*256+m][o] = sum_d kvs[hd*256+m][d] * fcw[(hd*256+d)*256+o]
__global__ void k_mpre(const float* __restrict__ kvs, const float* __restrict__ fcw,
                       float* __restrict__ M) {
  __shared__ float arow[EMB];
  int bid = blockIdx.x; // hd*256+m
  int hd = bid >> 8;
  int t = threadIdx.x;
  arow[t] = kvs[(size_t)bid * EMB + t];
  __syncthreads();
  float acc = 0.f;
  const float* wp = fcw + (size_t)(hd * 256) * EMB + t;
#pragma unroll 4
  for (int d = 0; d < EMB; ++d) acc += arow[d] * wp[(size_t)d * EMB];
  M[(size_t)bid * EMB + t] = acc;
}

__global__ void k_cvec(const float* __restrict__ h_sum, const float* __restrict__ fcw,
                       float* __restrict__ c) {
  __shared__ float arow[EMB];
  int hd = blockIdx.x;
  int t = threadIdx.x;
  arow[t] = h_sum[t];
  __syncthreads();
  float acc = 0.f;
  const float* wp = fcw + (size_t)(hd * 256) * EMB + t;
#pragma unroll 4
  for (int d = 0; d < EMB; ++d) acc += arow[d] * wp[(size_t)d * EMB];
  c[hd * EMB + t] = acc;
}

// SpMM hop 1: fp32 input h, bf16 output
__global__ void k_spmm_f(const float* __restrict__ xin, const u16* __restrict__ msg,
                         const int* __restrict__ offs, const int* __restrict__ csr_col,
                         const float* __restrict__ csr_adj, u16* __restrict__ sout) {
  int tid = threadIdx.x;
  int n0 = blockIdx.x * 8;
  for (int nn = 0; nn < 8; ++nn) {
    int n = n0 + nn;
    float acc = bf2f(msg[(size_t)n * EMB + tid]);
    int e0 = offs[n], e1 = offs[n + 1];
    for (int s = e0; s < e1; ++s) {
      acc += csr_adj[s] * xin[(size_t)csr_col[s] * EMB + tid];
    }
    sout[(size_t)n * EMB + tid] = f2bf(acc);
  }
}

// SpMM hops 2,3: bf16 in/out
__global__ void k_spmm_b(const u16* __restrict__ xin, const u16* __restrict__ msg,
                         const int* __restrict__ offs, const int* __restrict__ csr_col,
                         const float* __restrict__ csr_adj, u16* __restrict__ sout) {
  int tid = threadIdx.x;
  int n0 = blockIdx.x * 8;
  for (int nn = 0; nn < 8; ++nn) {
    int n = n0 + nn;
    float acc = bf2f(msg[(size_t)n * EMB + tid]);
    int e0 = offs[n], e1 = offs[n + 1];
    for (int s = e0; s < e1; ++s) {
      acc += csr_adj[s] * bf2f(xin[(size_t)csr_col[s] * EMB + tid]);
    }
    sout[(size_t)n * EMB + tid] = f2bf(acc);
  }
}

// Fused: q-proj + normalize + attention output + x2 FC + residual + LN + relu
__global__ __launch_bounds__(256) void k_fused(
    const float* __restrict__ h, const u16* __restrict__ s1, const u16* __restrict__ s2,
    const u16* __restrict__ s3, const float* __restrict__ wq, const float* __restrict__ bq,
    const float* __restrict__ Mm, const float* __restrict__ cvec, const float* __restrict__ kss,
    const float* __restrict__ fcw, const float* __restrict__ fcb,
    const float* __restrict__ lg, const float* __restrict__ lb, float* __restrict__ hout) {
  __shared__ float hT[EMB * 33];  // 33 KB: h / segment tile (transposed)
  __shared__ u16 qT[EMB * 33];    // 16.5 KB: normalized q tile (bf16, transposed)
  int tid = threadIdx.x, og = tid & 63, wv = tid >> 6;
  int n0 = blockIdx.x * 32;
  for (int it = 0; it < 32; ++it) {
    int r = n0 + it;
    hT[tid * 33 + it] = (r < NN) ? h[(size_t)r * EMB + tid] : 0.f;
  }
  __syncthreads();
  float acc[8][4];
#pragma unroll
  for (int r = 0; r < 8; ++r)
#pragma unroll
    for (int j = 0; j < 4; ++j) acc[r][j] = hT[(og * 4 + j) * 33 + wv * 8 + r]; // residual

  // ---- attention (x1 @ fcw[:1024] folded via M, cvec) ----
  for (int hd = 0; hd < NH; ++hd) {
    float qa[8][4] = {};
    {
      const float* wp = wq + hd * 256 + og * 4;
#pragma unroll 4
      for (int k = 0; k < EMB; ++k) {
        float4 bv = *reinterpret_cast<const float4*>(wp + (size_t)k * HE);
        const float* ap = &hT[k * 33 + wv * 8];
#pragma unroll
        for (int r = 0; r < 8; ++r) {
          float a = ap[r];
          qa[r][0] += a * bv.x; qa[r][1] += a * bv.y;
          qa[r][2] += a * bv.z; qa[r][3] += a * bv.w;
        }
      }
    }
    float4 bias = *reinterpret_cast<const float4*>(bq + hd * 256 + og * 4);
    float4 kssv = *reinterpret_cast<const float4*>(kss + hd * 256 + og * 4);
    float rdv[8];
    __syncthreads(); // previous head's qT reads done
#pragma unroll
    for (int r = 0; r < 8; ++r) {
      float v0 = qa[r][0] + bias.x, v1 = qa[r][1] + bias.y;
      float v2 = qa[r][2] + bias.z, v3 = qa[r][3] + bias.w;
      float nr = v0 * v0 + v1 * v1 + v2 * v2 + v3 * v3;
#pragma unroll
      for (int m = 1; m < 64; m <<= 1) nr += __shfl_xor(nr, m, 64);
      float rn = rsqrtf(nr);
      v0 *= rn; v1 *= rn; v2 *= rn; v3 *= rn;
      int rowi = n0 + wv * 8 + r; // wave-uniform
      bool ok = rowi < NN;
      float dp = v0 * kssv.x + v1 * kssv.y + v2 * kssv.z + v3 * kssv.w;
#pragma unroll
      for (int m = 1; m < 64; m <<= 1) dp += __shfl_xor(dp, m, 64);
      rdv[r] = ok ? 1.f / (dp + (float)NN) : 0.f;
      int rl = wv * 8 + r;
      qT[(og * 4 + 0) * 33 + rl] = ok ? f2bf(v0) : (u16)0;
      qT[(og * 4 + 1) * 33 + rl] = ok ? f2bf(v1) : (u16)0;
      qT[(og * 4 + 2) * 33 + rl] = ok ? f2bf(v2) : (u16)0;
      qT[(og * 4 + 3) * 33 + rl] = ok ? f2bf(v3) : (u16)0;
    }
    __syncthreads();
    float tac[8][4] = {};
    const float* mp = Mm + (size_t)(hd * 256) * EMB + og * 4;
#pragma unroll 4
    for (int m = 0; m < EMB; ++m) {
      float4 mv = *reinterpret_cast<const float4*>(mp + (size_t)m * EMB);
      const u16* qp = &qT[m * 33 + wv * 8];
#pragma unroll
      for (int r = 0; r < 8; ++r) {
        float a = bf2f(qp[r]);
        tac[r][0] += a * mv.x; tac[r][1] += a * mv.y;
        tac[r][2] += a * mv.z; tac[r][3] += a * mv.w;
      }
    }
    float4 cv = *reinterpret_cast<const float4*>(cvec + hd * EMB + og * 4);
#pragma unroll
    for (int r = 0; r < 8; ++r) {
      acc[r][0] += (tac[r][0] + cv.x) * rdv[r];
      acc[r][1] += (tac[r][1] + cv.y) * rdv[r];
      acc[r][2] += (tac[r][2] + cv.z) * rdv[r];
      acc[r][3] += (tac[r][3] + cv.w) * rdv[r];
    }
  }

  // ---- x2 = [h|s1|s2|s3] @ fcw[1024:2048] ----
  for (int sg = 0; sg < 4; ++sg) {
    if (sg > 0) {
      const u16* sp = (sg == 1) ? s1 : (sg == 2) ? s2 : s3;
      __syncthreads();
      for (int it = 0; it < 32; ++it) {
        int r = n0 + it;
        hT[tid * 33 + it] = (r < NN) ? bf2f(sp[(size_t)r * EMB + tid]) : 0.f;
      }
      __syncthreads();
    }
    const float* wp = fcw + (size_t)(HE + sg * 256) * EMB + og * 4;
#pragma unroll 4
    for (int k = 0; k < EMB; ++k) {
      float4 bv = *reinterpret_cast<const float4*>(wp + (size_t)k * EMB);
      const float* ap = &hT[k * 33 + wv * 8];
#pragma unroll
      for (int r = 0; r < 8; ++r) {
        float a = ap[r];
        acc[r][0] += a * bv.x; acc[r][1] += a * bv.y;
        acc[r][2] += a * bv.z; acc[r][3] += a * bv.w;
      }
    }
  }

  float4 bias = *reinterpret_cast<const float4*>(fcb + og * 4);
  float4 gg = *reinterpret_cast<const float4*>(lg + og * 4);
  float4 bb = *reinterpret_cast<const float4*>(lb + og * 4);
#pragma unroll
  for (int r = 0; r < 8; ++r) {
    int rowi = n0 + wv * 8 + r;
    if (rowi >= NN) continue; // wave-uniform
    float v0 = acc[r][0] + bias.x, v1 = acc[r][1] + bias.y;
    float v2 = acc[r][2] + bias.z, v3 = acc[r][3] + bias.w;
    float s = v0 + v1 + v2 + v3;
    float q = v0 * v0 + v1 * v1 + v2 * v2 + v3 * v3;
#pragma unroll
    for (int m = 1; m < 64; m <<= 1) {
      s += __shfl_xor(s, m, 64);
      q += __shfl_xor(q, m, 64);
    }
    float mu = s * (1.f / 256.f);
    float var = q * (1.f / 256.f) - mu * mu;
    float rs = rsqrtf(var + 1e-5f);
    float o0 = fmaxf(0.f, (v0 - mu) * rs * gg.x + bb.x);
    float o1 = fmaxf(0.f, (v1 - mu) * rs * gg.y + bb.y);
    float o2 = fmaxf(0.f, (v2 - mu) * rs * gg.z + bb.z);
    float o3 = fmaxf(0.f, (v3 - mu) * rs * gg.w + bb.w);
    float4 o4 = {o0, o1, o2, o3};
    *reinterpret_cast<float4*>(hout + (size_t)rowi * EMB + og * 4) = o4;
  }
}

// ---------------- pooling / output ----------------

__global__ void k_pool(const float* __restrict__ h, const int* __restrict__ batch,
                       float* __restrict__ pooled) {
  int n = blockIdx.x, d = threadIdx.x;
  atomicAdd(&pooled[(size_t)batch[n] * EMB + d], h[(size_t)n * EMB + d]);
}

__global__ void k_out(const float* __restrict__ pooled, const float* __restrict__ gcnt,
                      const float* __restrict__ ow, const float* __restrict__ ob,
                      float* __restrict__ out) {
  __shared__ float prow[EMB];
  int g = blockIdx.x, t = threadIdx.x;
  float rc = 1.f / fmaxf(gcnt[g], 1.f);
  for (int i = t; i < EMB; i += TASKS) prow[i] = pooled[(size_t)g * EMB + i] * rc;
  __syncthreads();
  float acc = ob[t];
#pragma unroll 4
  for (int d = 0; d < EMB; ++d) acc += prow[d] * ow[d * TASKS + t];
  out[(size_t)g * TASKS + t] = acc;
}

// ---------------- launch ----------------

extern "C" void kernel_launch(void* const* d_in, const int* in_sizes, int n_in,
                              void* d_out, int out_size, void* d_ws, size_t ws_size,
                              hipStream_t stream) {
  const int* x = (const int*)d_in[0];
  const int* eidx = (const int*)d_in[1];
  const int* eattr = (const int*)d_in[2];
  const int* batch = (const int*)d_in[3];
  const float* aemb = (const float*)d_in[4];
  const float* bemb = (const float*)d_in[5];
  const float* wq = (const float*)d_in[6];
  const float* bq = (const float*)d_in[7];
  const float* wk = (const float*)d_in[8];
  const float* bk = (const float*)d_in[9];
  const float* fcw = (const float*)d_in[10];
  const float* fcb = (const float*)d_in[11];
  const float* lg = (const float*)d_in[12];
  const float* lb = (const float*)d_in[13];
  const float* ow = (const float*)d_in[14];
  const float* ob = (const float*)d_in[15];
  float* out = (float*)d_out;

  size_t off = 0;
  auto alloc = [&](size_t bytes) -> void* {
    void* r = (char*)d_ws + off;
    off += (bytes + 255) & ~(size_t)255;
    return r;
  };
  float* h_a = (float*)alloc((size_t)NN * EMB * 4);      // 51.2 MB
  float* h_b = (float*)alloc((size_t)NN * EMB * 4);      // 51.2 MB
  u16* region = (u16*)alloc((size_t)NN * HE * 2);        // 102.4 MB (kn, then msg/s1/s2/s3)
  u16* kn = region;
  u16* msg = region;
  u16* s1 = region + (size_t)NN * EMB;
  u16* s2 = region + (size_t)2 * NN * EMB;
  u16* s3 = region + (size_t)3 * NN * EMB;
  float* kvs_part = (float*)alloc((size_t)SLICES * HE * EMB * 4); // 16.8 MB
  float* kvs = (float*)alloc((size_t)HE * EMB * 4);
  float* Mm = (float*)alloc((size_t)HE * EMB * 4);
  float* cvec = (float*)alloc((size_t)NH * EMB * 4);
  float* ksh = (float*)alloc((size_t)(HE + EMB) * 4); // ks_sum | h_sum
  float* ks_sum = ksh;
  float* h_sum = ksh + HE;
  float* dinv_i = (float*)alloc((size_t)NN * 4);
  float* dinv_j = (float*)alloc((size_t)NN * 4);
  int* deg_i = (int*)alloc((size_t)NN * 4);
  int* deg_j = (int*)alloc((size_t)NN * 4);
  int* offs = (int*)alloc((size_t)(NN + 1) * 4);
  int* cursor = (int*)alloc((size_t)NN * 4);
  int* csr_col = (int*)alloc((size_t)NE * 4);
  float* csr_adj = (float*)alloc((size_t)NE * 4);
  int* csr_pack = (int*)alloc((size_t)NE * 4);
  float* pooled = (float*)alloc((size_t)NG * EMB * 4);
  float* gcnt = (float*)alloc((size_t)NG * 4);

  if (off > ws_size) {
    // sentinel: absmax ~1e6 tells us workspace is still too small
    k_fill<<<(out_size + 255) / 256, 256, 0, stream>>>(out, out_size, 1048576.f);
    return;
  }

  const int* row = eidx;
  const int* colp = eidx + NE;

  k_zero<<<(NN + 255) / 256, 256, 0, stream>>>((u32*)deg_i, NN);
  k_zero<<<(NN + 255) / 256, 256, 0, stream>>>((u32*)deg_j, NN);
  k_zero<<<(NN + 255) / 256, 256, 0, stream>>>((u32*)cursor, NN);
  k_zero<<<(NG + 255) / 256, 256, 0, stream>>>((u32*)gcnt, NG);
  k_zero<<<(NG * EMB + 255) / 256, 256, 0, stream>>>((u32*)pooled, NG * EMB);

  k_atom<<<NN, EMB, 0, stream>>>(x, aemb, h_a);
  k_deg<<<NE / 256, 256, 0, stream>>>(row, colp, deg_i, deg_j);
  k_dinv<<<(NN + 255) / 256, 256, 0, stream>>>(deg_i, deg_j, dinv_i, dinv_j);
  k_scan<<<1, 1024, 0, stream>>>(deg_i, offs);
  k_csr<<<NE / 256, 256, 0, stream>>>(row, colp, eattr, dinv_i, dinv_j, offs, cursor,
                                      csr_col, csr_adj, csr_pack);
  k_gcnt<<<(NN + 255) / 256, 256, 0, stream>>>(batch, gcnt);

  float* hc = h_a;
  float* hn = h_b;
  for (int l = 0; l < NL; ++l) {
    const float* fcw_l = fcw + (size_t)l * 2048 * EMB;
    k_zero<<<(HE + EMB + 255) / 256, 256, 0, stream>>>((u32*)ksh, HE + EMB);
    // --- phase 1: kn region holds k ---
    k_projk<<<GB32, 256, 0, stream>>>(hc, wk + (size_t)l * EMB * HE, bk + (size_t)l * HE,
                                      kn, ks_sum, h_sum);
    k_kvs<<<dim3(4, 16, SLICES), 256, 0, stream>>>(kn, hc, kvs_part);
    k_kvs_red<<<HE * EMB / 256, 256, 0, stream>>>(kvs_part, kvs);
    k_mpre<<<HE, 256, 0, stream>>>(kvs, fcw_l, Mm);
    k_cvec<<<NH, 256, 0, stream>>>(h_sum, fcw_l, cvec);
    // --- phase 2: kn dead; region becomes msg/s1/s2/s3 ---
    k_message<<<NN / 16, 256, 0, stream>>>(bemb + (size_t)l * 3 * 10 * EMB, offs, csr_adj,
                                           csr_pack, msg);
    k_spmm_f<<<NN / 8, 256, 0, stream>>>(hc, msg, offs, csr_col, csr_adj, s1);
    k_spmm_b<<<NN / 8, 256, 0, stream>>>(s1, msg, offs, csr_col, csr_adj, s2);
    k_spmm_b<<<NN / 8, 256, 0, stream>>>(s2, msg, offs, csr_col, csr_adj, s3);
    k_fused<<<GB32, 256, 0, stream>>>(hc, s1, s2, s3, wq + (size_t)l * EMB * HE,
                                      bq + (size_t)l * HE, Mm, cvec, ks_sum, fcw_l,
                                      fcb + (size_t)l * EMB, lg + (size_t)l * EMB,
                                      lb + (size_t)l * EMB, hn);
    float* tmp = hc; hc = hn; hn = tmp;
  }
  k_pool<<<NN, EMB, 0, stream>>>(hc, batch, pooled);
  k_out<<<NG, TASKS, 0, stream>>>(pooled, gcnt, ow, ob, out);
}

// Round 3
// 8698.607 us; speedup vs baseline: 1.4382x; 1.4382x over previous
//
#include <hip/hip_runtime.h>

#define DEV __device__ __forceinline__

constexpr int NN = 50000;
constexpr int NE = 800000;
constexpr int NG = 1024;
constexpr int EMB = 256;
constexpr int NH = 4;
constexpr int HE = 1024;   // NH*EMB
constexpr int NL = 4;
constexpr int TASKS = 128;
constexpr int SLICES = 16;
constexpr int CHUNK = (NN + SLICES - 1) / SLICES; // 3125
constexpr int GB64 = (NN + 63) / 64;              // 782

using u16 = unsigned short;
using u32 = unsigned int;

typedef __attribute__((ext_vector_type(8))) short short8;
typedef __attribute__((ext_vector_type(4))) float f32x4;

#define MFMA16(a8, b8, c4) __builtin_amdgcn_mfma_f32_16x16x32_bf16(a8, b8, c4, 0, 0, 0)

DEV u16 f2bf(float f) {
  u32 u = __float_as_uint(f);
  u32 r = (u + 0x7FFFu + ((u >> 16) & 1u)) >> 16;
  return (u16)r;
}
DEV float bf2f(u16 s) { return __uint_as_float(((u32)s) << 16); }
DEV short8 ld8(const u16* p) { return *reinterpret_cast<const short8*>(p); }

// ---------------- utility ----------------

__global__ void k_zero(u32* __restrict__ p, int n) {
  int i = blockIdx.x * 256 + threadIdx.x;
  if (i < n) p[i] = 0u;
}

__global__ void k_fill(float* __restrict__ p, int n, float v) {
  int i = blockIdx.x * 256 + threadIdx.x;
  if (i < n) p[i] = v;
}

// transpose-cast: out[b][c][r] (bf16) = in[b][r][c] (f32); R,C multiples of 32
__global__ void k_tcast(const float* __restrict__ in, u16* __restrict__ outp, int R, int C) {
  __shared__ float t[32][33];
  int b = blockIdx.z;
  const float* ip = in + (size_t)b * R * C;
  u16* op = outp + (size_t)b * R * C;
  int r0 = blockIdx.y * 32, c0 = blockIdx.x * 32;
  int tx = threadIdx.x & 31, ty = threadIdx.x >> 5; // 32 x 8
#pragma unroll
  for (int i = 0; i < 4; ++i) t[ty + i * 8][tx] = ip[(size_t)(r0 + ty + i * 8) * C + c0 + tx];
  __syncthreads();
#pragma unroll
  for (int i = 0; i < 4; ++i)
    op[(size_t)(c0 + ty + i * 8) * R + r0 + tx] = f2bf(t[tx][ty + i * 8]);
}

// ---------------- setup kernels ----------------

__global__ void k_atom(const int* __restrict__ x, const float* __restrict__ aemb,
                       float* __restrict__ h, u16* __restrict__ h_bf) {
  int n = blockIdx.x, d = threadIdx.x;
  const int* xr = x + n * 9;
  float acc = 0.f;
#pragma unroll
  for (int f = 0; f < 9; ++f) acc += aemb[(f * 100 + xr[f]) * EMB + d];
  h[(size_t)n * EMB + d] = acc;
  h_bf[(size_t)n * EMB + d] = f2bf(acc);
}

__global__ void k_deg(const int* __restrict__ row, const int* __restrict__ col,
                      int* __restrict__ deg_i, int* __restrict__ deg_j) {
  int e = blockIdx.x * 256 + threadIdx.x;
  if (e < NE) {
    atomicAdd(&deg_i[row[e]], 1);
    atomicAdd(&deg_j[col[e]], 1);
  }
}

__global__ void k_dinv(const int* __restrict__ deg_i, const int* __restrict__ deg_j,
                       float* __restrict__ di, float* __restrict__ dj) {
  int n = blockIdx.x * 256 + threadIdx.x;
  if (n < NN) {
    di[n] = deg_i[n] > 0 ? rsqrtf((float)deg_i[n]) : 0.f;
    dj[n] = deg_j[n] > 0 ? rsqrtf((float)deg_j[n]) : 0.f;
  }
}

__global__ void k_scan(const int* __restrict__ deg, int* __restrict__ offs) {
  __shared__ int tot[1024];
  int t = threadIdx.x;
  constexpr int PER = (NN + 1023) / 1024; // 49
  int lo = t * PER, hi = lo + PER;
  if (hi > NN) hi = NN;
  int s = 0;
  for (int i = lo; i < hi; ++i) s += deg[i];
  tot[t] = s;
  __syncthreads();
  for (int off = 1; off < 1024; off <<= 1) {
    int v = (t >= off) ? tot[t - off] : 0;
    __syncthreads();
    tot[t] += v;
    __syncthreads();
  }
  int run = (t == 0) ? 0 : tot[t - 1];
  for (int i = lo; i < hi; ++i) { offs[i] = run; run += deg[i]; }
  if (t == 0) offs[NN] = NE;
}

__global__ void k_csr(const int* __restrict__ row, const int* __restrict__ col,
                      const int* __restrict__ eattr, const float* __restrict__ di,
                      const float* __restrict__ dj, const int* __restrict__ offs,
                      int* __restrict__ cursor, int* __restrict__ csr_col,
                      float* __restrict__ csr_adj, int* __restrict__ csr_pack) {
  int e = blockIdx.x * 256 + threadIdx.x;
  if (e >= NE) return;
  int r = row[e], c = col[e];
  int slot = offs[r] + atomicAdd(&cursor[r], 1);
  csr_col[slot] = c;
  csr_adj[slot] = di[r] * dj[c];
  csr_pack[slot] = eattr[e * 3] | (eattr[e * 3 + 1] << 8) | (eattr[e * 3 + 2] << 16);
}

__global__ void k_gcnt(const int* __restrict__ batch, float* __restrict__ gcnt) {
  int n = blockIdx.x * 256 + threadIdx.x;
  if (n < NN) atomicAdd(&gcnt[batch[n]], 1.f);
}

// ---------------- per-layer kernels ----------------

__global__ void k_message(const float* __restrict__ bond, const int* __restrict__ offs,
                          const float* __restrict__ csr_adj, const int* __restrict__ csr_pack,
                          u16* __restrict__ msg) {
  __shared__ float tab[3 * 10 * EMB]; // 30 KB
  int tid = threadIdx.x;
  for (int i = tid; i < 3 * 10 * EMB; i += 256) tab[i] = bond[i];
  __syncthreads();
  int n0 = blockIdx.x * 16;
  for (int nn = 0; nn < 16; ++nn) {
    int n = n0 + nn;
    int e0 = offs[n], e1 = offs[n + 1];
    float acc = 0.f;
    for (int s = e0; s < e1; ++s) {
      float a = csr_adj[s];
      int pk = csr_pack[s];
      int a0 = pk & 255, a1 = (pk >> 8) & 255, a2 = (pk >> 16) & 255;
      acc += a * (tab[a0 * EMB + tid] + tab[(10 + a1) * EMB + tid] + tab[(20 + a2) * EMB + tid]);
    }
    msg[(size_t)n * EMB + tid] = f2bf(acc);
  }
}

// MFMA k-projection: 64 nodes/block, 4 waves = 4 row-blocks of 16.
// Computes k = h@Wk + bk per head, L2-normalizes rows, writes kn bf16,
// accumulates ks_sum (normalized col sums) and h_sum.
__global__ __launch_bounds__(256) void k_projk(
    const float* __restrict__ h, const u16* __restrict__ h_bf,
    const u16* __restrict__ wkT, const float* __restrict__ bk,
    u16* __restrict__ kn, float* __restrict__ ks_sum, float* __restrict__ h_sum) {
  __shared__ __align__(16) u16 aL[32 * 64 * 8]; // 32 KB [(k>>3)*64+row][8]
  __shared__ float red[4][EMB];
  __shared__ float bkL[HE];
  int tid = threadIdx.x;
  int lane = tid & 63, w = tid >> 6;
  int g = lane >> 4, s = lane & 15;
  int n0 = blockIdx.x * 64;
  int wrow = w * 16;
  for (int i = tid; i < HE; i += 256) bkL[i] = bk[i];
  { // stage A tile from h_bf
    int r = tid & 63, kq = tid >> 6;
#pragma unroll
    for (int ii = 0; ii < 8; ++ii) {
      int k = kq * 64 + ii * 8;
      int row = n0 + r;
      uint4 v = {0u, 0u, 0u, 0u};
      if (row < NN) v = *reinterpret_cast<const uint4*>(h_bf + (size_t)row * EMB + k);
      *reinterpret_cast<uint4*>(&aL[((k >> 3) * 64 + r) * 8]) = v;
    }
  }
  __syncthreads();
  { // h_sum (fp32, exact)
    float ss = 0.f;
    for (int r = 0; r < 64; ++r) {
      int row = n0 + r;
      if (row < NN) ss += h[(size_t)row * EMB + tid];
    }
    atomicAdd(&h_sum[tid], ss);
  }
  for (int hd = 0; hd < NH; ++hd) {
    f32x4 ka[16] = {};
#pragma unroll
    for (int k0 = 0; k0 < 256; k0 += 32) {
      short8 a = ld8(&aL[(((k0 >> 3) + g) * 64 + wrow + s) * 8]);
#pragma unroll
      for (int c = 0; c < 16; ++c) {
        short8 b = ld8(wkT + (size_t)(hd * 256 + c * 16 + s) * 256 + k0 + g * 8);
        ka[c] = MFMA16(a, b, ka[c]);
      }
    }
    // bias + sumsq
    float nr[4] = {0.f, 0.f, 0.f, 0.f};
#pragma unroll
    for (int c = 0; c < 16; ++c) {
      float bv = bkL[hd * 256 + c * 16 + s];
#pragma unroll
      for (int r = 0; r < 4; ++r) {
        ka[c][r] += bv;
        nr[r] += ka[c][r] * ka[c][r];
      }
    }
#pragma unroll
    for (int r = 0; r < 4; ++r) {
      nr[r] += __shfl_xor(nr[r], 1, 64);
      nr[r] += __shfl_xor(nr[r], 2, 64);
      nr[r] += __shfl_xor(nr[r], 4, 64);
      nr[r] += __shfl_xor(nr[r], 8, 64);
    }
    float rn[4];
#pragma unroll
    for (int r = 0; r < 4; ++r) {
      int row = n0 + wrow + g * 4 + r;
      rn[r] = (row < NN && nr[r] > 0.f) ? rsqrtf(nr[r]) : 0.f;
    }
    // normalize + store kn + column partials
    float cs[16];
#pragma unroll
    for (int c = 0; c < 16; ++c) {
      float p = 0.f;
#pragma unroll
      for (int r = 0; r < 4; ++r) {
        float v = ka[c][r] * rn[r];
        ka[c][r] = v;
        p += v;
        int row = n0 + wrow + g * 4 + r;
        if (row < NN) kn[(size_t)row * HE + hd * 256 + c * 16 + s] = f2bf(v);
      }
      cs[c] = p;
    }
#pragma unroll
    for (int c = 0; c < 16; ++c) {
      cs[c] += __shfl_xor(cs[c], 16, 64);
      cs[c] += __shfl_xor(cs[c], 32, 64);
    }
    __syncthreads(); // red reuse from previous head
    if (g == 0) {
#pragma unroll
      for (int c = 0; c < 16; ++c) red[w][c * 16 + s] = cs[c];
    }
    __syncthreads();
    atomicAdd(&ks_sum[hd * 256 + tid & 255 ? hd * 256 + tid : hd * 256 + tid], 0.f); // no-op placeholder removed below
    if (tid < 256) {
      float tot = red[0][tid] + red[1][tid] + red[2][tid] + red[3][tid];
      atomicAdd(&ks_sum[hd * 256 + tid], tot);
    }
    __syncthreads();
  }
}

// kvs partials: part[sl][j][d] = sum_{n in slice} kn[n][j] * h_bf[n][d]
__global__ __launch_bounds__(256) void k_kvs(const u16* __restrict__ kn,
                                             const u16* __restrict__ h_bf,
                                             float* __restrict__ part) {
  __shared__ float As[32 * 64];
  __shared__ float Bs[32 * 64];
  int tid = threadIdx.x;
  int tx = tid & 15, ty = tid >> 4;
  int d0 = blockIdx.x * 64, j0 = blockIdx.y * 64, sl = blockIdx.z;
  int nb = sl * CHUNK, neend = nb + CHUNK;
  if (neend > NN) neend = NN;
  float acc[4][4] = {};
  int kk = tid >> 3;
  int off8 = (tid & 7) * 8;
  for (int k0 = nb; k0 < neend; k0 += 32) {
    int row = k0 + kk;
    if (row < neend) {
      uint4 ra = *reinterpret_cast<const uint4*>(kn + (size_t)row * HE + j0 + off8);
      As[kk * 64 + off8 + 0] = bf2f(ra.x & 0xffff);
      As[kk * 64 + off8 + 1] = bf2f(ra.x >> 16);
      As[kk * 64 + off8 + 2] = bf2f(ra.y & 0xffff);
      As[kk * 64 + off8 + 3] = bf2f(ra.y >> 16);
      As[kk * 64 + off8 + 4] = bf2f(ra.z & 0xffff);
      As[kk * 64 + off8 + 5] = bf2f(ra.z >> 16);
      As[kk * 64 + off8 + 6] = bf2f(ra.w & 0xffff);
      As[kk * 64 + off8 + 7] = bf2f(ra.w >> 16);
      uint4 rb = *reinterpret_cast<const uint4*>(h_bf + (size_t)row * EMB + d0 + off8);
      Bs[kk * 64 + off8 + 0] = bf2f(rb.x & 0xffff);
      Bs[kk * 64 + off8 + 1] = bf2f(rb.x >> 16);
      Bs[kk * 64 + off8 + 2] = bf2f(rb.y & 0xffff);
      Bs[kk * 64 + off8 + 3] = bf2f(rb.y >> 16);
      Bs[kk * 64 + off8 + 4] = bf2f(rb.z & 0xffff);
      Bs[kk * 64 + off8 + 5] = bf2f(rb.z >> 16);
      Bs[kk * 64 + off8 + 6] = bf2f(rb.w & 0xffff);
      Bs[kk * 64 + off8 + 7] = bf2f(rb.w >> 16);
    } else {
#pragma unroll
      for (int q = 0; q < 8; ++q) { As[kk * 64 + off8 + q] = 0.f; Bs[kk * 64 + off8 + q] = 0.f; }
    }
    __syncthreads();
#pragma unroll
    for (int k2 = 0; k2 < 32; ++k2) {
      float4 a = *reinterpret_cast<const float4*>(&As[k2 * 64 + ty * 4]);
      float4 b = *reinterpret_cast<const float4*>(&Bs[k2 * 64 + tx * 4]);
      acc[0][0] += a.x * b.x; acc[0][1] += a.x * b.y; acc[0][2] += a.x * b.z; acc[0][3] += a.x * b.w;
      acc[1][0] += a.y * b.x; acc[1][1] += a.y * b.y; acc[1][2] += a.y * b.z; acc[1][3] += a.y * b.w;
      acc[2][0] += a.z * b.x; acc[2][1] += a.z * b.y; acc[2][2] += a.z * b.z; acc[2][3] += a.z * b.w;
      acc[3][0] += a.w * b.x; acc[3][1] += a.w * b.y; acc[3][2] += a.w * b.z; acc[3][3] += a.w * b.w;
    }
    __syncthreads();
  }
  float* op = part + (size_t)sl * HE * EMB;
#pragma unroll
  for (int i = 0; i < 4; ++i) {
    float4 o4 = {acc[i][0], acc[i][1], acc[i][2], acc[i][3]};
    *reinterpret_cast<float4*>(op + (size_t)(j0 + ty * 4 + i) * EMB + d0 + tx * 4) = o4;
  }
}

__global__ void k_kvs_red(const float* __restrict__ part, float* __restrict__ kvs) {
  int i = blockIdx.x * 256 + threadIdx.x;
  float s = 0.f;
#pragma unroll
  for (int sl = 0; sl < SLICES; ++sl) s += part[(size_t)sl * HE * EMB + i];
  kvs[i] = s;
}

// M[hd*256+m][o] = sum_d kvs[hd*256+m][d] * fcw[(hd*256+d)*256+o]  (fp32)
__global__ void k_mpre(const float* __restrict__ kvs, const float* __restrict__ fcw,
                       float* __restrict__ M) {
  __shared__ float arow[EMB];
  int bid = blockIdx.x; // hd*256+m
  int hd = bid >> 8;
  int t = threadIdx.x;
  arow[t] = kvs[(size_t)bid * EMB + t];
  __syncthreads();
  float acc = 0.f;
  const float* wp = fcw + (size_t)(hd * 256) * EMB + t;
#pragma unroll 4
  for (int d = 0; d < EMB; ++d) acc += arow[d] * wp[(size_t)d * EMB];
  M[(size_t)bid * EMB + t] = acc;
}

__global__ void k_cvec(const float* __restrict__ h_sum, const float* __restrict__ fcw,
                       float* __restrict__ c) {
  __shared__ float arow[EMB];
  int hd = blockIdx.x;
  int t = threadIdx.x;
  arow[t] = h_sum[t];
  __syncthreads();
  float acc = 0.f;
  const float* wp = fcw + (size_t)(hd * 256) * EMB + t;
#pragma unroll 4
  for (int d = 0; d < EMB; ++d) acc += arow[d] * wp[(size_t)d * EMB];
  c[hd * EMB + t] = acc;
}

// SpMM: bf16 in/out
__global__ void k_spmm(const u16* __restrict__ xin, const u16* __restrict__ msg,
                       const int* __restrict__ offs, const int* __restrict__ csr_col,
                       const float* __restrict__ csr_adj, u16* __restrict__ sout) {
  int tid = threadIdx.x;
  int n0 = blockIdx.x * 8;
  for (int nn = 0; nn < 8; ++nn) {
    int n = n0 + nn;
    float acc = bf2f(msg[(size_t)n * EMB + tid]);
    int e0 = offs[n], e1 = offs[n + 1];
    for (int s = e0; s < e1; ++s) {
      acc += csr_adj[s] * bf2f(xin[(size_t)csr_col[s] * EMB + tid]);
    }
    sout[(size_t)n * EMB + tid] = f2bf(acc);
  }
}

// MFMA fused layer tail: q-proj + normalize + attention (via M,c) + x2 FC
// + residual + LN + relu; in-place update of h and h_bf. 64 nodes/block.
__global__ __launch_bounds__(256) void k_fused(
    float* __restrict__ h, u16* __restrict__ h_bf,
    const u16* __restrict__ s1, const u16* __restrict__ s2, const u16* __restrict__ s3,
    const u16* __restrict__ wqT, const float* __restrict__ bq,
    const u16* __restrict__ MT, const float* __restrict__ cvec, const float* __restrict__ kss,
    const u16* __restrict__ fcwT, const float* __restrict__ fcb,
    const float* __restrict__ lg, const float* __restrict__ lb) {
  __shared__ __align__(16) u16 aL[32 * 64 * 8]; // 32 KB
  __shared__ __align__(16) u16 qL[32 * 64 * 8]; // 32 KB
  __shared__ float kssL[HE], bqL[HE], cvL[HE];  // 12 KB
  __shared__ float fcbL[EMB], lgL[EMB], lbL[EMB];
  int tid = threadIdx.x;
  int lane = tid & 63, w = tid >> 6;
  int g = lane >> 4, s = lane & 15;
  int n0 = blockIdx.x * 64;
  int wrow = w * 16;
  for (int i = tid; i < HE; i += 256) {
    kssL[i] = kss[i];
    bqL[i] = bq[i];
    cvL[i] = cvec[i];
  }
  if (tid < EMB) { fcbL[tid] = fcb[tid]; lgL[tid] = lg[tid]; lbL[tid] = lb[tid]; }
  { // stage h tile (bf16 A-layout)
    int r = tid & 63, kq = tid >> 6;
#pragma unroll
    for (int ii = 0; ii < 8; ++ii) {
      int k = kq * 64 + ii * 8;
      int row = n0 + r;
      uint4 v = {0u, 0u, 0u, 0u};
      if (row < NN) v = *reinterpret_cast<const uint4*>(h_bf + (size_t)row * EMB + k);
      *reinterpret_cast<uint4*>(&aL[((k >> 3) * 64 + r) * 8]) = v;
    }
  }
  __syncthreads();

  f32x4 zac[16] = {};

  // ---- attention ----
  for (int hd = 0; hd < NH; ++hd) {
    f32x4 qa[16] = {};
#pragma unroll
    for (int k0 = 0; k0 < 256; k0 += 32) {
      short8 a = ld8(&aL[(((k0 >> 3) + g) * 64 + wrow + s) * 8]);
#pragma unroll
      for (int c = 0; c < 16; ++c) {
        short8 b = ld8(wqT + (size_t)(hd * 256 + c * 16 + s) * 256 + k0 + g * 8);
        qa[c] = MFMA16(a, b, qa[c]);
      }
    }
    float nr[4] = {0.f, 0.f, 0.f, 0.f};
    float dp[4] = {0.f, 0.f, 0.f, 0.f};
#pragma unroll
    for (int c = 0; c < 16; ++c) {
      float bv = bqL[hd * 256 + c * 16 + s];
      float kv = kssL[hd * 256 + c * 16 + s];
#pragma unroll
      for (int r = 0; r < 4; ++r) {
        qa[c][r] += bv;
        nr[r] += qa[c][r] * qa[c][r];
        dp[r] += qa[c][r] * kv;
      }
    }
#pragma unroll
    for (int r = 0; r < 4; ++r) {
      nr[r] += __shfl_xor(nr[r], 1, 64);
      nr[r] += __shfl_xor(nr[r], 2, 64);
      nr[r] += __shfl_xor(nr[r], 4, 64);
      nr[r] += __shfl_xor(nr[r], 8, 64);
      dp[r] += __shfl_xor(dp[r], 1, 64);
      dp[r] += __shfl_xor(dp[r], 2, 64);
      dp[r] += __shfl_xor(dp[r], 4, 64);
      dp[r] += __shfl_xor(dp[r], 8, 64);
    }
    float rn[4], rdv[4];
#pragma unroll
    for (int r = 0; r < 4; ++r) {
      int row = n0 + wrow + g * 4 + r;
      rn[r] = (row < NN && nr[r] > 0.f) ? rsqrtf(nr[r]) : 0.f;
      rdv[r] = 1.f / (dp[r] * rn[r] + (float)NN);
    }
    __syncthreads(); // previous head's qL reads done
#pragma unroll
    for (int c = 0; c < 16; ++c) {
      int m = c * 16 + s;
#pragma unroll
      for (int r = 0; r < 4; ++r) {
        int row = wrow + g * 4 + r;
        qL[((m >> 3) * 64 + row) * 8 + (m & 7)] = f2bf(qa[c][r] * rn[r]);
      }
    }
    __syncthreads();
    f32x4 ta[16] = {};
#pragma unroll
    for (int k0 = 0; k0 < 256; k0 += 32) {
      short8 a = ld8(&qL[(((k0 >> 3) + g) * 64 + wrow + s) * 8]);
#pragma unroll
      for (int c = 0; c < 16; ++c) {
        short8 b = ld8(MT + (size_t)(hd * 256 + c * 16 + s) * 256 + k0 + g * 8);
        ta[c] = MFMA16(a, b, ta[c]);
      }
    }
#pragma unroll
    for (int c = 0; c < 16; ++c) {
      float cv = cvL[hd * 256 + c * 16 + s];
#pragma unroll
      for (int r = 0; r < 4; ++r) zac[c][r] += (ta[c][r] + cv) * rdv[r];
    }
  }

  // ---- x2 = [h|s1|s2|s3] @ fcw[1024:2048] ----
  for (int sg = 0; sg < 4; ++sg) {
    if (sg > 0) {
      const u16* sp = (sg == 1) ? s1 : (sg == 2) ? s2 : s3;
      __syncthreads();
      int r = tid & 63, kq = tid >> 6;
#pragma unroll
      for (int ii = 0; ii < 8; ++ii) {
        int k = kq * 64 + ii * 8;
        int row = n0 + r;
        uint4 v = {0u, 0u, 0u, 0u};
        if (row < NN) v = *reinterpret_cast<const uint4*>(sp + (size_t)row * EMB + k);
        *reinterpret_cast<uint4*>(&aL[((k >> 3) * 64 + r) * 8]) = v;
      }
      __syncthreads();
    }
#pragma unroll
    for (int k0 = 0; k0 < 256; k0 += 32) {
      short8 a = ld8(&aL[(((k0 >> 3) + g) * 64 + wrow + s) * 8]);
#pragma unroll
      for (int c = 0; c < 16; ++c) {
        short8 b = ld8(fcwT + (size_t)(c * 16 + s) * 2048 + 1024 + sg * 256 + k0 + g * 8);
        zac[c] = MFMA16(a, b, zac[c]);
      }
    }
  }

  // ---- epilogue: + fc_b + residual h, LN, relu, store ----
  float sm[4] = {0.f, 0.f, 0.f, 0.f}, sq[4] = {0.f, 0.f, 0.f, 0.f};
#pragma unroll
  for (int c = 0; c < 16; ++c) {
    int col = c * 16 + s;
    float fb = fcbL[col];
#pragma unroll
    for (int r = 0; r < 4; ++r) {
      int row = n0 + wrow + g * 4 + r;
      float hv = (row < NN) ? h[(size_t)row * EMB + col] : 0.f;
      float v = zac[c][r] + fb + hv;
      zac[c][r] = v;
      sm[r] += v;
      sq[r] += v * v;
    }
  }
#pragma unroll
  for (int r = 0; r < 4; ++r) {
    sm[r] += __shfl_xor(sm[r], 1, 64);
    sm[r] += __shfl_xor(sm[r], 2, 64);
    sm[r] += __shfl_xor(sm[r], 4, 64);
    sm[r] += __shfl_xor(sm[r], 8, 64);
    sq[r] += __shfl_xor(sq[r], 1, 64);
    sq[r] += __shfl_xor(sq[r], 2, 64);
    sq[r] += __shfl_xor(sq[r], 4, 64);
    sq[r] += __shfl_xor(sq[r], 8, 64);
  }
  float mu[4], rs[4];
#pragma unroll
  for (int r = 0; r < 4; ++r) {
    mu[r] = sm[r] * (1.f / 256.f);
    float var = sq[r] * (1.f / 256.f) - mu[r] * mu[r];
    rs[r] = rsqrtf(var + 1e-5f);
  }
#pragma unroll
  for (int c = 0; c < 16; ++c) {
    int col = c * 16 + s;
    float gg = lgL[col], bb = lbL[col];
#pragma unroll
    for (int r = 0; r < 4; ++r) {
      int row = n0 + wrow + g * 4 + r;
      if (row < NN) {
        float o = fmaxf(0.f, (zac[c][r] - mu[r]) * rs[r] * gg + bb);
        h[(size_t)row * EMB + col] = o;
        h_bf[(size_t)row * EMB + col] = f2bf(o);
      }
    }
  }
}

// ---------------- pooling / output ----------------

__global__ void k_pool(const float* __restrict__ h, const int* __restrict__ batch,
                       float* __restrict__ pooled) {
  int n = blockIdx.x, d = threadIdx.x;
  atomicAdd(&pooled[(size_t)batch[n] * EMB + d], h[(size_t)n * EMB + d]);
}

__global__ void k_out(const float* __restrict__ pooled, const float* __restrict__ gcnt,
                      const float* __restrict__ ow, const float* __restrict__ ob,
                      float* __restrict__ out) {
  __shared__ float prow[EMB];
  int g = blockIdx.x, t = threadIdx.x;
  float rc = 1.f / fmaxf(gcnt[g], 1.f);
  for (int i = t; i < EMB; i += TASKS) prow[i] = pooled[(size_t)g * EMB + i] * rc;
  __syncthreads();
  float acc = ob[t];
#pragma unroll 4
  for (int d = 0; d < EMB; ++d) acc += prow[d] * ow[d * TASKS + t];
  out[(size_t)g * TASKS + t] = acc;
}

// ---------------- launch ----------------

extern "C" void kernel_launch(void* const* d_in, const int* in_sizes, int n_in,
                              void* d_out, int out_size, void* d_ws, size_t ws_size,
                              hipStream_t stream) {
  const int* x = (const int*)d_in[0];
  const int* eidx = (const int*)d_in[1];
  const int* eattr = (const int*)d_in[2];
  const int* batch = (const int*)d_in[3];
  const float* aemb = (const float*)d_in[4];
  const float* bemb = (const float*)d_in[5];
  const float* wq = (const float*)d_in[6];
  const float* bq = (const float*)d_in[7];
  const float* wk = (const float*)d_in[8];
  const float* bk = (const float*)d_in[9];
  const float* fcw = (const float*)d_in[10];
  const float* fcb = (const float*)d_in[11];
  const float* lg = (const float*)d_in[12];
  const float* lb = (const float*)d_in[13];
  const float* ow = (const float*)d_in[14];
  const float* ob = (const float*)d_in[15];
  float* out = (float*)d_out;

  size_t off = 0;
  auto alloc = [&](size_t bytes) -> void* {
    void* r = (char*)d_ws + off;
    off += (bytes + 255) & ~(size_t)255;
    return r;
  };
  float* h = (float*)alloc((size_t)NN * EMB * 4);        // 51.2 MB
  u16* h_bf = (u16*)alloc((size_t)NN * EMB * 2);         // 25.6 MB
  u16* region = (u16*)alloc((size_t)NN * HE * 2);        // 102.4 MB (kn | msg,s1,s2,s3)
  u16* kn = region;
  u16* msg = region;
  u16* s1 = region + (size_t)NN * EMB;
  u16* s2 = region + (size_t)2 * NN * EMB;
  u16* s3 = region + (size_t)3 * NN * EMB;
  float* kvs_part = (float*)alloc((size_t)SLICES * HE * EMB * 4); // 16.8 MB
  float* kvs = (float*)alloc((size_t)HE * EMB * 4);
  float* Mm = (float*)alloc((size_t)HE * EMB * 4);
  u16* MT = (u16*)alloc((size_t)HE * EMB * 2);
  u16* wqT = (u16*)alloc((size_t)NL * HE * EMB * 2);   // 2.1 MB
  u16* wkT = (u16*)alloc((size_t)NL * HE * EMB * 2);   // 2.1 MB
  u16* fcwT = (u16*)alloc((size_t)NL * 2048 * EMB * 2); // 4.2 MB
  float* cvec = (float*)alloc((size_t)NH * EMB * 4);
  float* ksh = (float*)alloc((size_t)(HE + EMB) * 4); // ks_sum | h_sum
  float* ks_sum = ksh;
  float* h_sum = ksh + HE;
  float* dinv_i = (float*)alloc((size_t)NN * 4);
  float* dinv_j = (float*)alloc((size_t)NN * 4);
  int* deg_i = (int*)alloc((size_t)NN * 4);
  int* deg_j = (int*)alloc((size_t)NN * 4);
  int* offs = (int*)alloc((size_t)(NN + 1) * 4);
  int* cursor = (int*)alloc((size_t)NN * 4);
  int* csr_col = (int*)alloc((size_t)NE * 4);
  float* csr_adj = (float*)alloc((size_t)NE * 4);
  int* csr_pack = (int*)alloc((size_t)NE * 4);
  float* pooled = (float*)alloc((size_t)NG * EMB * 4);
  float* gcnt = (float*)alloc((size_t)NG * 4);

  if (off > ws_size) {
    k_fill<<<(out_size + 255) / 256, 256, 0, stream>>>(out, out_size, 1048576.f);
    return;
  }

  const int* row = eidx;
  const int* colp = eidx + NE;

  k_zero<<<(NN + 255) / 256, 256, 0, stream>>>((u32*)deg_i, NN);
  k_zero<<<(NN + 255) / 256, 256, 0, stream>>>((u32*)deg_j, NN);
  k_zero<<<(NN + 255) / 256, 256, 0, stream>>>((u32*)cursor, NN);
  k_zero<<<(NG + 255) / 256, 256, 0, stream>>>((u32*)gcnt, NG);
  k_zero<<<(NG * EMB + 255) / 256, 256, 0, stream>>>((u32*)pooled, NG * EMB);

  // one-time weight transpose-casts
  k_tcast<<<dim3(32, 8, NL), 256, 0, stream>>>(wq, wqT, 256, 1024);
  k_tcast<<<dim3(32, 8, NL), 256, 0, stream>>>(wk, wkT, 256, 1024);
  k_tcast<<<dim3(8, 64, NL), 256, 0, stream>>>(fcw, fcwT, 2048, 256);

  k_atom<<<NN, EMB, 0, stream>>>(x, aemb, h, h_bf);
  k_deg<<<NE / 256, 256, 0, stream>>>(row, colp, deg_i, deg_j);
  k_dinv<<<(NN + 255) / 256, 256, 0, stream>>>(deg_i, deg_j, dinv_i, dinv_j);
  k_scan<<<1, 1024, 0, stream>>>(deg_i, offs);
  k_csr<<<NE / 256, 256, 0, stream>>>(row, colp, eattr, dinv_i, dinv_j, offs, cursor,
                                      csr_col, csr_adj, csr_pack);
  k_gcnt<<<(NN + 255) / 256, 256, 0, stream>>>(batch, gcnt);

  for (int l = 0; l < NL; ++l) {
    const float* fcw_l = fcw + (size_t)l * 2048 * EMB;
    k_zero<<<(HE + EMB + 255) / 256, 256, 0, stream>>>((u32*)ksh, HE + EMB);
    // --- phase 1: region holds kn ---
    k_projk<<<GB64, 256, 0, stream>>>(h, h_bf, wkT + (size_t)l * HE * EMB, bk + (size_t)l * HE,
                                      kn, ks_sum, h_sum);
    k_kvs<<<dim3(4, 16, SLICES), 256, 0, stream>>>(kn, h_bf, kvs_part);
    k_kvs_red<<<HE * EMB / 256, 256, 0, stream>>>(kvs_part, kvs);
    k_mpre<<<HE, 256, 0, stream>>>(kvs, fcw_l, Mm);
    k_tcast<<<dim3(8, 8, NH), 256, 0, stream>>>(Mm, MT, 256, 256);
    k_cvec<<<NH, 256, 0, stream>>>(h_sum, fcw_l, cvec);
    // --- phase 2: kn dead; region becomes msg/s1/s2/s3 ---
    k_message<<<NN / 16, 256, 0, stream>>>(bemb + (size_t)l * 3 * 10 * EMB, offs, csr_adj,
                                           csr_pack, msg);
    k_spmm<<<NN / 8, 256, 0, stream>>>(h_bf, msg, offs, csr_col, csr_adj, s1);
    k_spmm<<<NN / 8, 256, 0, stream>>>(s1, msg, offs, csr_col, csr_adj, s2);
    k_spmm<<<NN / 8, 256, 0, stream>>>(s2, msg, offs, csr_col, csr_adj, s3);
    k_fused<<<GB64, 256, 0, stream>>>(h, h_bf, s1, s2, s3, wqT + (size_t)l * HE * EMB,
                                      bq + (size_t)l * HE, MT, cvec, ks_sum,
                                      fcwT + (size_t)l * 2048 * EMB, fcb + (size_t)l * EMB,
                                      lg + (size_t)l * EMB, lb + (size_t)l * EMB);
  }
  k_pool<<<NN, EMB, 0, stream>>>(h, batch, pooled);
  k_out<<<NG, TASKS, 0, stream>>>(pooled, gcnt, ow, ob, out);
}

// Round 4
// 6205.216 us; speedup vs baseline: 2.0161x; 1.4018x over previous
//
#include <hip/hip_runtime.h>

#define DEV __device__ __forceinline__

constexpr int NN = 50000;
constexpr int NE = 800000;
constexpr int NG = 1024;
constexpr int EMB = 256;
constexpr int NH = 4;
constexpr int HE = 1024;   // NH*EMB
constexpr int NL = 4;
constexpr int TASKS = 128;
constexpr int NS = 50048;            // padded nodes (multiple of 64)
constexpr int NCH = NS / 32;         // 1564 K-chunks for kvs
constexpr int KVS_SL = 32;           // kvs n-slices
constexpr int GB64 = NS / 64;        // 782 (covers pad exactly)

using u16 = unsigned short;
using u32 = unsigned int;

typedef __attribute__((ext_vector_type(8))) short short8;
typedef __attribute__((ext_vector_type(4))) float f32x4;

#define MFMA16(a8, b8, c4) __builtin_amdgcn_mfma_f32_16x16x32_bf16(a8, b8, c4, 0, 0, 0)

DEV u16 f2bf(float f) {
  u32 u = __float_as_uint(f);
  u32 r = (u + 0x7FFFu + ((u >> 16) & 1u)) >> 16;
  return (u16)r;
}
DEV float bf2f(u16 s) { return __uint_as_float(((u32)s) << 16); }
DEV short8 ld8(const u16* p) { return *reinterpret_cast<const short8*>(p); }

// ---------------- utility ----------------

__global__ void k_zero(u32* __restrict__ p, int n) {
  int i = blockIdx.x * 256 + threadIdx.x;
  if (i < n) p[i] = 0u;
}

__global__ void k_fill(float* __restrict__ p, int n, float v) {
  int i = blockIdx.x * 256 + threadIdx.x;
  if (i < n) p[i] = v;
}

// transpose-cast: out[b][c][r] (bf16) = in[b][r][c] (f32); R,C multiples of 32
__global__ void k_tcast(const float* __restrict__ in, u16* __restrict__ outp, int R, int C) {
  __shared__ float t[32][33];
  int b = blockIdx.z;
  const float* ip = in + (size_t)b * R * C;
  u16* op = outp + (size_t)b * R * C;
  int r0 = blockIdx.y * 32, c0 = blockIdx.x * 32;
  int tx = threadIdx.x & 31, ty = threadIdx.x >> 5; // 32 x 8
#pragma unroll
  for (int i = 0; i < 4; ++i) t[ty + i * 8][tx] = ip[(size_t)(r0 + ty + i * 8) * C + c0 + tx];
  __syncthreads();
#pragma unroll
  for (int i = 0; i < 4; ++i)
    op[(size_t)(c0 + ty + i * 8) * R + r0 + tx] = f2bf(t[tx][ty + i * 8]);
}

// h transpose: hT[d][n] = h_bf[n][d], zero-padded to NS
__global__ void k_htr(const u16* __restrict__ h_bf, u16* __restrict__ hT) {
  __shared__ u16 t[64][72];
  int tid = threadIdx.x;
  int n0 = blockIdx.x * 64, d0 = blockIdx.y * 64;
#pragma unroll
  for (int rr = 0; rr < 2; ++rr) {
    int nl = rr * 32 + (tid >> 3);
    int dd = (tid & 7) * 8;
    uint4 v = {0u, 0u, 0u, 0u};
    int n = n0 + nl;
    if (n < NN) v = *reinterpret_cast<const uint4*>(h_bf + (size_t)n * EMB + d0 + dd);
    *reinterpret_cast<uint4*>(&t[nl][dd]) = v;
  }
  __syncthreads();
  int dl = tid & 63, q = tid >> 6;
  u32 wbuf[8];
#pragma unroll
  for (int i = 0; i < 8; ++i)
    wbuf[i] = (u32)t[q * 16 + 2 * i][dl] | ((u32)t[q * 16 + 2 * i + 1][dl] << 16);
  uint4 o0 = {wbuf[0], wbuf[1], wbuf[2], wbuf[3]};
  uint4 o1 = {wbuf[4], wbuf[5], wbuf[6], wbuf[7]};
  *reinterpret_cast<uint4*>(hT + (size_t)(d0 + dl) * NS + n0 + q * 16) = o0;
  *reinterpret_cast<uint4*>(hT + (size_t)(d0 + dl) * NS + n0 + q * 16 + 8) = o1;
}

// ---------------- setup kernels ----------------

__global__ void k_atom(const int* __restrict__ x, const float* __restrict__ aemb,
                       u16* __restrict__ h_bf) {
  int n = blockIdx.x, d = threadIdx.x;
  const int* xr = x + n * 9;
  float acc = 0.f;
#pragma unroll
  for (int f = 0; f < 9; ++f) acc += aemb[(f * 100 + xr[f]) * EMB + d];
  h_bf[(size_t)n * EMB + d] = f2bf(acc);
}

__global__ void k_deg(const int* __restrict__ row, const int* __restrict__ col,
                      int* __restrict__ deg_i, int* __restrict__ deg_j) {
  int e = blockIdx.x * 256 + threadIdx.x;
  if (e < NE) {
    atomicAdd(&deg_i[row[e]], 1);
    atomicAdd(&deg_j[col[e]], 1);
  }
}

__global__ void k_dinv(const int* __restrict__ deg_i, const int* __restrict__ deg_j,
                       float* __restrict__ di, float* __restrict__ dj) {
  int n = blockIdx.x * 256 + threadIdx.x;
  if (n < NN) {
    di[n] = deg_i[n] > 0 ? rsqrtf((float)deg_i[n]) : 0.f;
    dj[n] = deg_j[n] > 0 ? rsqrtf((float)deg_j[n]) : 0.f;
  }
}

__global__ void k_scan(const int* __restrict__ deg, int* __restrict__ offs) {
  __shared__ int tot[1024];
  int t = threadIdx.x;
  constexpr int PER = (NN + 1023) / 1024; // 49
  int lo = t * PER, hi = lo + PER;
  if (hi > NN) hi = NN;
  int s = 0;
  for (int i = lo; i < hi; ++i) s += deg[i];
  tot[t] = s;
  __syncthreads();
  for (int off = 1; off < 1024; off <<= 1) {
    int v = (t >= off) ? tot[t - off] : 0;
    __syncthreads();
    tot[t] += v;
    __syncthreads();
  }
  int run = (t == 0) ? 0 : tot[t - 1];
  for (int i = lo; i < hi; ++i) { offs[i] = run; run += deg[i]; }
  if (t == 0) offs[NN] = NE;
}

__global__ void k_csr(const int* __restrict__ row, const int* __restrict__ col,
                      const int* __restrict__ eattr, const float* __restrict__ di,
                      const float* __restrict__ dj, const int* __restrict__ offs,
                      int* __restrict__ cursor, int* __restrict__ csr_col,
                      float* __restrict__ csr_adj, int* __restrict__ csr_pack) {
  int e = blockIdx.x * 256 + threadIdx.x;
  if (e >= NE) return;
  int r = row[e], c = col[e];
  int slot = offs[r] + atomicAdd(&cursor[r], 1);
  csr_col[slot] = c;
  csr_adj[slot] = di[r] * dj[c];
  csr_pack[slot] = eattr[e * 3] | (eattr[e * 3 + 1] << 8) | (eattr[e * 3 + 2] << 16);
}

__global__ void k_gcnt(const int* __restrict__ batch, float* __restrict__ gcnt) {
  int n = blockIdx.x * 256 + threadIdx.x;
  if (n < NN) atomicAdd(&gcnt[batch[n]], 1.f);
}

// ---------------- per-layer kernels ----------------

__global__ void k_message(const float* __restrict__ bond, const int* __restrict__ offs,
                          const float* __restrict__ csr_adj, const int* __restrict__ csr_pack,
                          u16* __restrict__ msg) {
  __shared__ float tab[3 * 10 * EMB]; // 30 KB
  int tid = threadIdx.x;
  for (int i = tid; i < 3 * 10 * EMB; i += 256) tab[i] = bond[i];
  __syncthreads();
  int n0 = blockIdx.x * 16;
  for (int nn = 0; nn < 16; ++nn) {
    int n = n0 + nn;
    int e0 = offs[n], e1 = offs[n + 1];
    float acc = 0.f;
    for (int s = e0; s < e1; ++s) {
      float a = csr_adj[s];
      int pk = csr_pack[s];
      int a0 = pk & 255, a1 = (pk >> 8) & 255, a2 = (pk >> 16) & 255;
      acc += a * (tab[a0 * EMB + tid] + tab[(10 + a1) * EMB + tid] + tab[(20 + a2) * EMB + tid]);
    }
    msg[(size_t)n * EMB + tid] = f2bf(acc);
  }
}

// MFMA k-projection: 64 nodes/block. k = h@Wk + bk per head, row-normalize,
// write knT[j][n] (bf16, zero-padded), accumulate ks_sum and h_sum.
__global__ __launch_bounds__(256) void k_projk(
    const u16* __restrict__ h_bf, const u16* __restrict__ wkT, const float* __restrict__ bk,
    u16* __restrict__ knT, float* __restrict__ ks_sum, float* __restrict__ h_sum) {
  __shared__ __align__(16) u16 aL[32 * 64 * 8]; // 32 KB
  __shared__ float red[4][EMB];
  __shared__ float bkL[HE];
  int tid = threadIdx.x;
  int lane = tid & 63, w = tid >> 6;
  int g = lane >> 4, s = lane & 15;
  int n0 = blockIdx.x * 64;
  int wrow = w * 16;
  for (int i = tid; i < HE; i += 256) bkL[i] = bk[i];
  { // stage A tile from h_bf
    int r = tid & 63, kq = tid >> 6;
#pragma unroll
    for (int ii = 0; ii < 8; ++ii) {
      int k = kq * 64 + ii * 8;
      int row = n0 + r;
      uint4 v = {0u, 0u, 0u, 0u};
      if (row < NN) v = *reinterpret_cast<const uint4*>(h_bf + (size_t)row * EMB + k);
      *reinterpret_cast<uint4*>(&aL[((k >> 3) * 64 + r) * 8]) = v;
    }
  }
  __syncthreads();
  { // h_sum (column sums over the tile, from bf16)
    float ss = 0.f;
#pragma unroll 8
    for (int r = 0; r < 64; ++r) ss += bf2f(aL[((tid >> 3) * 64 + r) * 8 + (tid & 7)]);
    atomicAdd(&h_sum[tid], ss);
  }
  for (int hd = 0; hd < NH; ++hd) {
    f32x4 ka[16] = {};
#pragma unroll
    for (int k0 = 0; k0 < 256; k0 += 32) {
      short8 a = ld8(&aL[(((k0 >> 3) + g) * 64 + wrow + s) * 8]);
#pragma unroll
      for (int c = 0; c < 16; ++c) {
        short8 b = ld8(wkT + (size_t)(hd * 256 + c * 16 + s) * 256 + k0 + g * 8);
        ka[c] = MFMA16(a, b, ka[c]);
      }
    }
    float nr[4] = {0.f, 0.f, 0.f, 0.f};
#pragma unroll
    for (int c = 0; c < 16; ++c) {
      float bv = bkL[hd * 256 + c * 16 + s];
#pragma unroll
      for (int r = 0; r < 4; ++r) {
        ka[c][r] += bv;
        nr[r] += ka[c][r] * ka[c][r];
      }
    }
#pragma unroll
    for (int r = 0; r < 4; ++r) {
      nr[r] += __shfl_xor(nr[r], 1, 64);
      nr[r] += __shfl_xor(nr[r], 2, 64);
      nr[r] += __shfl_xor(nr[r], 4, 64);
      nr[r] += __shfl_xor(nr[r], 8, 64);
    }
    float rn[4];
#pragma unroll
    for (int r = 0; r < 4; ++r) {
      int row = n0 + wrow + g * 4 + r;
      rn[r] = (row < NN && nr[r] > 0.f) ? rsqrtf(nr[r]) : 0.f; // 0 for pad rows
    }
    float cs[16];
#pragma unroll
    for (int c = 0; c < 16; ++c) {
      float v0 = ka[c][0] * rn[0], v1 = ka[c][1] * rn[1];
      float v2 = ka[c][2] * rn[2], v3 = ka[c][3] * rn[3];
      cs[c] = v0 + v1 + v2 + v3;
      ushort4 pk;
      pk.x = f2bf(v0); pk.y = f2bf(v1); pk.z = f2bf(v2); pk.w = f2bf(v3);
      // knT row j = hd*256 + c*16 + s, n = n0 + wrow + g*4 (+0..3); pads get 0
      *reinterpret_cast<ushort4*>(knT + (size_t)(hd * 256 + c * 16 + s) * NS + n0 + wrow + g * 4) = pk;
    }
#pragma unroll
    for (int c = 0; c < 16; ++c) {
      cs[c] += __shfl_xor(cs[c], 16, 64);
      cs[c] += __shfl_xor(cs[c], 32, 64);
    }
    __syncthreads();
    if (g == 0) {
#pragma unroll
      for (int c = 0; c < 16; ++c) red[w][c * 16 + s] = cs[c];
    }
    __syncthreads();
    float tot = red[0][tid] + red[1][tid] + red[2][tid] + red[3][tid];
    atomicAdd(&ks_sum[hd * 256 + tid], tot);
    __syncthreads();
  }
}

// MFMA kvs: kvs[j][d] += sum_n knT[j][n] * hT[d][n]; direct global fragments.
__global__ __launch_bounds__(256) void k_kvs(const u16* __restrict__ knT,
                                             const u16* __restrict__ hT,
                                             float* __restrict__ kvs) {
  int tid = threadIdx.x;
  int lane = tid & 63, w = tid >> 6;
  int s = lane & 15, g = lane >> 4;
  int j0 = blockIdx.x * 64;
  int sl = blockIdx.y;
  f32x4 acc[4][4] = {}; // [jf][df]
  const u16* ap = knT + (size_t)(j0 + s) * NS + g * 8;
  const u16* bp = hT + (size_t)(w * 64 + s) * NS + g * 8;
  for (int ch = sl; ch < NCH; ch += KVS_SL) {
    int n0 = ch * 32;
    short8 bfr[4];
#pragma unroll
    for (int df = 0; df < 4; ++df) bfr[df] = ld8(bp + (size_t)df * 16 * NS + n0);
#pragma unroll
    for (int jf = 0; jf < 4; ++jf) {
      short8 a = ld8(ap + (size_t)jf * 16 * NS + n0);
#pragma unroll
      for (int df = 0; df < 4; ++df) acc[jf][df] = MFMA16(a, bfr[df], acc[jf][df]);
    }
  }
#pragma unroll
  for (int jf = 0; jf < 4; ++jf)
#pragma unroll
    for (int df = 0; df < 4; ++df)
#pragma unroll
      for (int r = 0; r < 4; ++r)
        atomicAdd(&kvs[(size_t)(j0 + jf * 16 + g * 4 + r) * EMB + w * 64 + df * 16 + s],
                  acc[jf][df][r]);
}

// M[hd*256+m][o] = sum_d kvs[hd*256+m][d] * fcw[(hd*256+d)*256+o]  (fp32)
__global__ void k_mpre(const float* __restrict__ kvs, const float* __restrict__ fcw,
                       float* __restrict__ M) {
  __shared__ float arow[EMB];
  int bid = blockIdx.x; // hd*256+m
  int hd = bid >> 8;
  int t = threadIdx.x;
  arow[t] = kvs[(size_t)bid * EMB + t];
  __syncthreads();
  float acc = 0.f;
  const float* wp = fcw + (size_t)(hd * 256) * EMB + t;
#pragma unroll 4
  for (int d = 0; d < EMB; ++d) acc += arow[d] * wp[(size_t)d * EMB];
  M[(size_t)bid * EMB + t] = acc;
}

__global__ void k_cvec(const float* __restrict__ h_sum, const float* __restrict__ fcw,
                       float* __restrict__ c) {
  __shared__ float arow[EMB];
  int hd = blockIdx.x;
  int t = threadIdx.x;
  arow[t] = h_sum[t];
  __syncthreads();
  float acc = 0.f;
  const float* wp = fcw + (size_t)(hd * 256) * EMB + t;
#pragma unroll 4
  for (int d = 0; d < EMB; ++d) acc += arow[d] * wp[(size_t)d * EMB];
  c[hd * EMB + t] = acc;
}

// SpMM: wave-per-node, lane owns 4 cols; bf16 in/out, 4-edge unroll.
__global__ __launch_bounds__(256) void k_spmm(
    const u16* __restrict__ xin, const u16* __restrict__ msg,
    const int* __restrict__ offs, const int* __restrict__ csr_col,
    const float* __restrict__ csr_adj, u16* __restrict__ sout) {
  int lane = threadIdx.x & 63, w = threadIdx.x >> 6;
  int n = blockIdx.x * 4 + w;
  if (n >= NN) return;
  int c4 = lane * 4;
  uint2 m = *reinterpret_cast<const uint2*>(msg + (size_t)n * EMB + c4);
  float a0 = bf2f(m.x & 0xffff), a1 = bf2f(m.x >> 16);
  float a2 = bf2f(m.y & 0xffff), a3 = bf2f(m.y >> 16);
  int e0 = offs[n], e1 = offs[n + 1];
  int s = e0;
  for (; s + 4 <= e1; s += 4) {
    int col0 = csr_col[s], col1 = csr_col[s + 1], col2 = csr_col[s + 2], col3 = csr_col[s + 3];
    float w0 = csr_adj[s], w1 = csr_adj[s + 1], w2 = csr_adj[s + 2], w3 = csr_adj[s + 3];
    uint2 r0 = *reinterpret_cast<const uint2*>(xin + (size_t)col0 * EMB + c4);
    uint2 r1 = *reinterpret_cast<const uint2*>(xin + (size_t)col1 * EMB + c4);
    uint2 r2 = *reinterpret_cast<const uint2*>(xin + (size_t)col2 * EMB + c4);
    uint2 r3 = *reinterpret_cast<const uint2*>(xin + (size_t)col3 * EMB + c4);
    a0 += w0 * bf2f(r0.x & 0xffff) + w1 * bf2f(r1.x & 0xffff) + w2 * bf2f(r2.x & 0xffff) + w3 * bf2f(r3.x & 0xffff);
    a1 += w0 * bf2f(r0.x >> 16)    + w1 * bf2f(r1.x >> 16)    + w2 * bf2f(r2.x >> 16)    + w3 * bf2f(r3.x >> 16);
    a2 += w0 * bf2f(r0.y & 0xffff) + w1 * bf2f(r1.y & 0xffff) + w2 * bf2f(r2.y & 0xffff) + w3 * bf2f(r3.y & 0xffff);
    a3 += w0 * bf2f(r0.y >> 16)    + w1 * bf2f(r1.y >> 16)    + w2 * bf2f(r2.y >> 16)    + w3 * bf2f(r3.y >> 16);
  }
  for (; s < e1; ++s) {
    int col = csr_col[s];
    float wv = csr_adj[s];
    uint2 r0 = *reinterpret_cast<const uint2*>(xin + (size_t)col * EMB + c4);
    a0 += wv * bf2f(r0.x & 0xffff);
    a1 += wv * bf2f(r0.x >> 16);
    a2 += wv * bf2f(r0.y & 0xffff);
    a3 += wv * bf2f(r0.y >> 16);
  }
  ushort4 o;
  o.x = f2bf(a0); o.y = f2bf(a1); o.z = f2bf(a2); o.w = f2bf(a3);
  *reinterpret_cast<ushort4*>(sout + (size_t)n * EMB + c4) = o;
}

// MFMA fused layer tail: q-proj + normalize + attention (rdv folded into q-frag)
// + x2 FC + residual + LN + relu; in-place update of h_bf. 64 nodes/block.
__global__ __launch_bounds__(256) void k_fused(
    u16* __restrict__ h_bf,
    const u16* __restrict__ s1, const u16* __restrict__ s2, const u16* __restrict__ s3,
    const u16* __restrict__ wqT, const float* __restrict__ bq,
    const u16* __restrict__ MT, const float* __restrict__ cvec, const float* __restrict__ kss,
    const u16* __restrict__ fcwT, const float* __restrict__ fcb,
    const float* __restrict__ lg, const float* __restrict__ lb) {
  __shared__ __align__(16) u16 aL[32 * 64 * 8]; // 32 KB
  __shared__ __align__(16) u16 qL[32 * 64 * 8]; // 32 KB
  __shared__ float kssL[HE], bqL[HE], cvL[HE];  // 12 KB
  __shared__ float fcbL[EMB], lgL[EMB], lbL[EMB];
  int tid = threadIdx.x;
  int lane = tid & 63, w = tid >> 6;
  int g = lane >> 4, s = lane & 15;
  int n0 = blockIdx.x * 64;
  int wrow = w * 16;
  for (int i = tid; i < HE; i += 256) {
    kssL[i] = kss[i];
    bqL[i] = bq[i];
    cvL[i] = cvec[i];
  }
  if (tid < EMB) { fcbL[tid] = fcb[tid]; lgL[tid] = lg[tid]; lbL[tid] = lb[tid]; }
  { // stage h tile
    int r = tid & 63, kq = tid >> 6;
#pragma unroll
    for (int ii = 0; ii < 8; ++ii) {
      int k = kq * 64 + ii * 8;
      int row = n0 + r;
      uint4 v = {0u, 0u, 0u, 0u};
      if (row < NN) v = *reinterpret_cast<const uint4*>(h_bf + (size_t)row * EMB + k);
      *reinterpret_cast<uint4*>(&aL[((k >> 3) * 64 + r) * 8]) = v;
    }
  }
  __syncthreads();

  // residual init from staged h
  f32x4 zac[16];
#pragma unroll
  for (int c = 0; c < 16; ++c) {
    int col = c * 16 + s;
#pragma unroll
    for (int r = 0; r < 4; ++r)
      zac[c][r] = bf2f(aL[((col >> 3) * 64 + wrow + g * 4 + r) * 8 + (col & 7)]);
  }

  // ---- attention ----
  for (int hd = 0; hd < NH; ++hd) {
    f32x4 qa[16] = {};
#pragma unroll
    for (int k0 = 0; k0 < 256; k0 += 32) {
      short8 a = ld8(&aL[(((k0 >> 3) + g) * 64 + wrow + s) * 8]);
#pragma unroll
      for (int c = 0; c < 16; ++c) {
        short8 b = ld8(wqT + (size_t)(hd * 256 + c * 16 + s) * 256 + k0 + g * 8);
        qa[c] = MFMA16(a, b, qa[c]);
      }
    }
    float nr[4] = {0.f, 0.f, 0.f, 0.f};
    float dp[4] = {0.f, 0.f, 0.f, 0.f};
#pragma unroll
    for (int c = 0; c < 16; ++c) {
      float bv = bqL[hd * 256 + c * 16 + s];
      float kv = kssL[hd * 256 + c * 16 + s];
#pragma unroll
      for (int r = 0; r < 4; ++r) {
        qa[c][r] += bv;
        nr[r] += qa[c][r] * qa[c][r];
        dp[r] += qa[c][r] * kv;
      }
    }
#pragma unroll
    for (int r = 0; r < 4; ++r) {
      nr[r] += __shfl_xor(nr[r], 1, 64);
      nr[r] += __shfl_xor(nr[r], 2, 64);
      nr[r] += __shfl_xor(nr[r], 4, 64);
      nr[r] += __shfl_xor(nr[r], 8, 64);
      dp[r] += __shfl_xor(dp[r], 1, 64);
      dp[r] += __shfl_xor(dp[r], 2, 64);
      dp[r] += __shfl_xor(dp[r], 4, 64);
      dp[r] += __shfl_xor(dp[r], 8, 64);
    }
    float sc[4], rdv[4];
#pragma unroll
    for (int r = 0; r < 4; ++r) {
      int row = n0 + wrow + g * 4 + r;
      float rn = (row < NN && nr[r] > 0.f) ? rsqrtf(nr[r]) : 0.f;
      rdv[r] = 1.f / (dp[r] * rn + (float)NN);
      sc[r] = rn * rdv[r]; // fold normalize AND 1/denom into the q fragment
    }
    __syncthreads(); // previous head's qL reads done
#pragma unroll
    for (int c = 0; c < 16; ++c) {
      int m = c * 16 + s;
#pragma unroll
      for (int r = 0; r < 4; ++r)
        qL[((m >> 3) * 64 + wrow + g * 4 + r) * 8 + (m & 7)] = f2bf(qa[c][r] * sc[r]);
    }
    __syncthreads();
#pragma unroll
    for (int k0 = 0; k0 < 256; k0 += 32) {
      short8 a = ld8(&qL[(((k0 >> 3) + g) * 64 + wrow + s) * 8]);
#pragma unroll
      for (int c = 0; c < 16; ++c) {
        short8 b = ld8(MT + (size_t)(hd * 256 + c * 16 + s) * 256 + k0 + g * 8);
        zac[c] = MFMA16(a, b, zac[c]); // accumulate (q*rdv)@M directly
      }
    }
#pragma unroll
    for (int c = 0; c < 16; ++c) {
      float cv = cvL[hd * 256 + c * 16 + s];
#pragma unroll
      for (int r = 0; r < 4; ++r) zac[c][r] += cv * rdv[r];
    }
  }

  // ---- x2 = [h|s1|s2|s3] @ fcw[1024:2048] ----
  for (int sg = 0; sg < 4; ++sg) {
    if (sg > 0) {
      const u16* sp = (sg == 1) ? s1 : (sg == 2) ? s2 : s3;
      __syncthreads();
      int r = tid & 63, kq = tid >> 6;
#pragma unroll
      for (int ii = 0; ii < 8; ++ii) {
        int k = kq * 64 + ii * 8;
        int row = n0 + r;
        uint4 v = {0u, 0u, 0u, 0u};
        if (row < NN) v = *reinterpret_cast<const uint4*>(sp + (size_t)row * EMB + k);
        *reinterpret_cast<uint4*>(&aL[((k >> 3) * 64 + r) * 8]) = v;
      }
      __syncthreads();
    }
#pragma unroll
    for (int k0 = 0; k0 < 256; k0 += 32) {
      short8 a = ld8(&aL[(((k0 >> 3) + g) * 64 + wrow + s) * 8]);
#pragma unroll
      for (int c = 0; c < 16; ++c) {
        short8 b = ld8(fcwT + (size_t)(c * 16 + s) * 2048 + 1024 + sg * 256 + k0 + g * 8);
        zac[c] = MFMA16(a, b, zac[c]);
      }
    }
  }

  // ---- epilogue: + fc_b, LN, relu, store h_bf ----
  float sm[4] = {0.f, 0.f, 0.f, 0.f}, sq[4] = {0.f, 0.f, 0.f, 0.f};
#pragma unroll
  for (int c = 0; c < 16; ++c) {
    int col = c * 16 + s;
    float fb = fcbL[col];
#pragma unroll
    for (int r = 0; r < 4; ++r) {
      float v = zac[c][r] + fb;
      zac[c][r] = v;
      sm[r] += v;
      sq[r] += v * v;
    }
  }
#pragma unroll
  for (int r = 0; r < 4; ++r) {
    sm[r] += __shfl_xor(sm[r], 1, 64);
    sm[r] += __shfl_xor(sm[r], 2, 64);
    sm[r] += __shfl_xor(sm[r], 4, 64);
    sm[r] += __shfl_xor(sm[r], 8, 64);
    sq[r] += __shfl_xor(sq[r], 1, 64);
    sq[r] += __shfl_xor(sq[r], 2, 64);
    sq[r] += __shfl_xor(sq[r], 4, 64);
    sq[r] += __shfl_xor(sq[r], 8, 64);
  }
  float mu[4], rs[4];
#pragma unroll
  for (int r = 0; r < 4; ++r) {
    mu[r] = sm[r] * (1.f / 256.f);
    float var = sq[r] * (1.f / 256.f) - mu[r] * mu[r];
    rs[r] = rsqrtf(var + 1e-5f);
  }
#pragma unroll
  for (int c = 0; c < 16; ++c) {
    int col = c * 16 + s;
    float gg = lgL[col], bb = lbL[col];
#pragma unroll
    for (int r = 0; r < 4; ++r) {
      int row = n0 + wrow + g * 4 + r;
      if (row < NN) {
        float o = fmaxf(0.f, (zac[c][r] - mu[r]) * rs[r] * gg + bb);
        h_bf[(size_t)row * EMB + col] = f2bf(o);
      }
    }
  }
}

// ---------------- pooling / output ----------------

// segmented pool: batch is sorted, flush on graph change
__global__ void k_pool(const u16* __restrict__ h_bf, const int* __restrict__ batch,
                       float* __restrict__ pooled) {
  int t = threadIdx.x; // col
  int n0 = blockIdx.x * 64;
  if (n0 >= NN) return;
  int nend = n0 + 64;
  if (nend > NN) nend = NN;
  float run = 0.f;
  int cur = batch[n0];
  for (int n = n0; n < nend; ++n) {
    int b = batch[n];
    if (b != cur) {
      atomicAdd(&pooled[(size_t)cur * EMB + t], run);
      run = 0.f;
      cur = b;
    }
    run += bf2f(h_bf[(size_t)n * EMB + t]);
  }
  atomicAdd(&pooled[(size_t)cur * EMB + t], run);
}

__global__ void k_out(const float* __restrict__ pooled, const float* __restrict__ gcnt,
                      const float* __restrict__ ow, const float* __restrict__ ob,
                      float* __restrict__ out) {
  __shared__ float prow[EMB];
  int g = blockIdx.x, t = threadIdx.x;
  float rc = 1.f / fmaxf(gcnt[g], 1.f);
  for (int i = t; i < EMB; i += TASKS) prow[i] = pooled[(size_t)g * EMB + i] * rc;
  __syncthreads();
  float acc = ob[t];
#pragma unroll 4
  for (int d = 0; d < EMB; ++d) acc += prow[d] * ow[d * TASKS + t];
  out[(size_t)g * TASKS + t] = acc;
}

// ---------------- launch ----------------

extern "C" void kernel_launch(void* const* d_in, const int* in_sizes, int n_in,
                              void* d_out, int out_size, void* d_ws, size_t ws_size,
                              hipStream_t stream) {
  const int* x = (const int*)d_in[0];
  const int* eidx = (const int*)d_in[1];
  const int* eattr = (const int*)d_in[2];
  const int* batch = (const int*)d_in[3];
  const float* aemb = (const float*)d_in[4];
  const float* bemb = (const float*)d_in[5];
  const float* wq = (const float*)d_in[6];
  const float* bq = (const float*)d_in[7];
  const float* wk = (const float*)d_in[8];
  const float* bk = (const float*)d_in[9];
  const float* fcw = (const float*)d_in[10];
  const float* fcb = (const float*)d_in[11];
  const float* lg = (const float*)d_in[12];
  const float* lb = (const float*)d_in[13];
  const float* ow = (const float*)d_in[14];
  const float* ob = (const float*)d_in[15];
  float* out = (float*)d_out;

  size_t off = 0;
  auto alloc = [&](size_t bytes) -> void* {
    void* r = (char*)d_ws + off;
    off += (bytes + 255) & ~(size_t)255;
    return r;
  };
  u16* h_bf = (u16*)alloc((size_t)NN * EMB * 2);        // 25.6 MB
  u16* region = (u16*)alloc((size_t)HE * NS * 2);       // 102.5 MB (knT | msg,s1,s2,s3)
  u16* knT = region;
  u16* msg = region;
  u16* s1 = region + (size_t)NN * EMB;
  u16* s2 = region + (size_t)2 * NN * EMB;
  u16* s3 = region + (size_t)3 * NN * EMB;
  u16* hT = (u16*)alloc((size_t)EMB * NS * 2);          // 25.6 MB
  float* kvs = (float*)alloc((size_t)HE * EMB * 4);     // 1 MB
  float* Mm = (float*)alloc((size_t)HE * EMB * 4);      // 1 MB
  u16* MT = (u16*)alloc((size_t)HE * EMB * 2);          // 0.5 MB
  u16* wqT = (u16*)alloc((size_t)NL * HE * EMB * 2);    // 2.1 MB
  u16* wkT = (u16*)alloc((size_t)NL * HE * EMB * 2);    // 2.1 MB
  u16* fcwT = (u16*)alloc((size_t)NL * 2048 * EMB * 2); // 4.2 MB
  float* cvec = (float*)alloc((size_t)NH * EMB * 4);
  float* ksh = (float*)alloc((size_t)(HE + EMB) * 4); // ks_sum | h_sum
  float* ks_sum = ksh;
  float* h_sum = ksh + HE;
  float* dinv_i = (float*)alloc((size_t)NN * 4);
  float* dinv_j = (float*)alloc((size_t)NN * 4);
  int* deg_i = (int*)alloc((size_t)NN * 4);
  int* deg_j = (int*)alloc((size_t)NN * 4);
  int* offs = (int*)alloc((size_t)(NN + 1) * 4);
  int* cursor = (int*)alloc((size_t)NN * 4);
  int* csr_col = (int*)alloc((size_t)NE * 4);
  float* csr_adj = (float*)alloc((size_t)NE * 4);
  int* csr_pack = (int*)alloc((size_t)NE * 4);
  float* pooled = (float*)alloc((size_t)NG * EMB * 4);
  float* gcnt = (float*)alloc((size_t)NG * 4);

  if (off > ws_size) {
    k_fill<<<(out_size + 255) / 256, 256, 0, stream>>>(out, out_size, 1048576.f);
    return;
  }

  const int* row = eidx;
  const int* colp = eidx + NE;

  k_zero<<<(NN + 255) / 256, 256, 0, stream>>>((u32*)deg_i, NN);
  k_zero<<<(NN + 255) / 256, 256, 0, stream>>>((u32*)deg_j, NN);
  k_zero<<<(NN + 255) / 256, 256, 0, stream>>>((u32*)cursor, NN);
  k_zero<<<(NG + 255) / 256, 256, 0, stream>>>((u32*)gcnt, NG);
  k_zero<<<(NG * EMB + 255) / 256, 256, 0, stream>>>((u32*)pooled, NG * EMB);

  // one-time weight transpose-casts
  k_tcast<<<dim3(32, 8, NL), 256, 0, stream>>>(wq, wqT, 256, 1024);
  k_tcast<<<dim3(32, 8, NL), 256, 0, stream>>>(wk, wkT, 256, 1024);
  k_tcast<<<dim3(8, 64, NL), 256, 0, stream>>>(fcw, fcwT, 2048, 256);

  k_atom<<<NN, EMB, 0, stream>>>(x, aemb, h_bf);
  k_deg<<<NE / 256, 256, 0, stream>>>(row, colp, deg_i, deg_j);
  k_dinv<<<(NN + 255) / 256, 256, 0, stream>>>(deg_i, deg_j, dinv_i, dinv_j);
  k_scan<<<1, 1024, 0, stream>>>(deg_i, offs);
  k_csr<<<NE / 256, 256, 0, stream>>>(row, colp, eattr, dinv_i, dinv_j, offs, cursor,
                                      csr_col, csr_adj, csr_pack);
  k_gcnt<<<(NN + 255) / 256, 256, 0, stream>>>(batch, gcnt);

  for (int l = 0; l < NL; ++l) {
    const float* fcw_l = fcw + (size_t)l * 2048 * EMB;
    k_zero<<<(HE + EMB + 255) / 256, 256, 0, stream>>>((u32*)ksh, HE + EMB);
    k_zero<<<(HE * EMB + 255) / 256, 256, 0, stream>>>((u32*)kvs, HE * EMB);
    // --- phase 1: region holds knT ---
    k_projk<<<GB64, 256, 0, stream>>>(h_bf, wkT + (size_t)l * HE * EMB, bk + (size_t)l * HE,
                                      knT, ks_sum, h_sum);
    k_htr<<<dim3(GB64, 4), 256, 0, stream>>>(h_bf, hT);
    k_kvs<<<dim3(16, KVS_SL), 256, 0, stream>>>(knT, hT, kvs);
    k_mpre<<<HE, 256, 0, stream>>>(kvs, fcw_l, Mm);
    k_tcast<<<dim3(8, 8, NH), 256, 0, stream>>>(Mm, MT, 256, 256);
    k_cvec<<<NH, 256, 0, stream>>>(h_sum, fcw_l, cvec);
    // --- phase 2: knT dead; region becomes msg/s1/s2/s3 ---
    k_message<<<NN / 16, 256, 0, stream>>>(bemb + (size_t)l * 3 * 10 * EMB, offs, csr_adj,
                                           csr_pack, msg);
    k_spmm<<<NN / 4, 256, 0, stream>>>(h_bf, msg, offs, csr_col, csr_adj, s1);
    k_spmm<<<NN / 4, 256, 0, stream>>>(s1, msg, offs, csr_col, csr_adj, s2);
    k_spmm<<<NN / 4, 256, 0, stream>>>(s2, msg, offs, csr_col, csr_adj, s3);
    k_fused<<<GB64, 256, 0, stream>>>(h_bf, s1, s2, s3, wqT + (size_t)l * HE * EMB,
                                      bq + (size_t)l * HE, MT, cvec, ks_sum,
                                      fcwT + (size_t)l * 2048 * EMB, fcb + (size_t)l * EMB,
                                      lg + (size_t)l * EMB, lb + (size_t)l * EMB);
  }
  k_pool<<<(NN + 63) / 64, 256, 0, stream>>>(h_bf, batch, pooled);
  k_out<<<NG, TASKS, 0, stream>>>(pooled, gcnt, ow, ob, out);
}